// Round 4
// baseline (1060.094 us; speedup 1.0000x reference)
//
#include <hip/hip_runtime.h>
#include <hip/hip_bf16.h>

typedef __attribute__((ext_vector_type(8))) short short8;
typedef __attribute__((ext_vector_type(4))) float floatx4;

#define NB 4
#define GRIDD 128
#define GRID3 (128*128*128)
#define C 128
#define KSLOT 32
#define CTX_BPB 128

static __device__ __forceinline__ unsigned short f2bf(float f){
  unsigned u = __builtin_bit_cast(unsigned, f);
  unsigned r = (u + 0x7FFFu + ((u >> 16) & 1u)) >> 16;
  return (unsigned short)r;
}
static __device__ __forceinline__ float bf2f(unsigned short h){
  unsigned u = ((unsigned)h) << 16;
  return __builtin_bit_cast(float, u);
}

// ---------- prep: bf16 conversions + transposes ----------
__global__ void prepk(const float* __restrict__ feats, const float* __restrict__ convw,
                      const float* __restrict__ inw,
                      unsigned short* __restrict__ Fb, unsigned short* __restrict__ Wt,
                      unsigned short* __restrict__ Wq, unsigned short* __restrict__ WkvT,
                      long total1)
{
  const long stride = (long)gridDim.x * blockDim.x;
  const long i0 = (long)blockIdx.x * blockDim.x + threadIdx.x;
  // feats -> bf16, vectorized 4-wide
  const long q4 = total1 >> 2;
  const float4* f4 = reinterpret_cast<const float4*>(feats);
  ushort4* fb4 = reinterpret_cast<ushort4*>(Fb);
  for (long i = i0; i < q4; i += stride){
    const float4 v = f4[i];
    ushort4 o; o.x = f2bf(v.x); o.y = f2bf(v.y); o.z = f2bf(v.z); o.w = f2bf(v.w);
    fb4[i] = o;
  }
  // Wt[k][cout][cin] = convw[k][cin][cout]
  for (long i = i0; i < 27L*C*C; i += stride){
    long k = i >> 14; long r = (i >> 7) & 127; long c = i & 127;
    Wt[i] = f2bf(convw[(k << 14) + (c << 7) + r]);
  }
  for (long i = i0; i < C*C; i += stride) Wq[i] = f2bf(inw[i]);
  // WkvT[which][i][cout] = inw[(1+which)*C*C + cout*C + i]
  for (long i = i0; i < 2L*C*C; i += stride){
    long which = i >> 14, rem = i & 16383, ii = rem >> 7, cout = rem & 127;
    WkvT[i] = f2bf(inw[((1 + which) << 14) + (cout << 7) + ii]);
  }
}

// ---------- fold W2 = (bw[:, :128]+bw[:, 128:]) @ outw ; b2 = Wcf @ outb ----------
__global__ __launch_bounds__(128) void w2k(const float* __restrict__ bw,
                                           const float* __restrict__ outw,
                                           const float* __restrict__ outb,
                                           unsigned short* __restrict__ W2b,
                                           float* __restrict__ b2){
  const int o = blockIdx.x, i = threadIdx.x;
  __shared__ float wcf[128];
  __shared__ float red[128];
  const float w_i = bw[(size_t)o*256 + i] + bw[(size_t)o*256 + 128 + i];
  wcf[i] = w_i;
  red[i] = w_i * outb[i];
  __syncthreads();
  float acc = 0.f;
  #pragma unroll 8
  for (int j = 0; j < 128; j++) acc = fmaf(wcf[j], outw[j*128 + i], acc);
  W2b[o*128 + i] = f2bf(acc);
  for (int s = 64; s > 0; s >>= 1){
    if (i < s) red[i] += red[i + s];
    __syncthreads();
  }
  if (i == 0) b2[o] = red[0];
}

// ---------- scatter active sites into dense grid hash ----------
__global__ void scatterk(const int* __restrict__ coords, int* __restrict__ gh, int N){
  int p = blockIdx.x * 256 + threadIdx.x;
  if (p < N){
    int4 cr = *reinterpret_cast<const int4*>(coords + (size_t)p * 4);
    gh[(((cr.x*GRIDD + cr.y)*GRIDD + cr.z)*GRIDD) + cr.w] = p;
  }
}

// ---------- phase 1: all 27 neighbor lookups per point, high MLP ----------
__global__ __launch_bounds__(256) void jlistk(const int* __restrict__ coords,
                                              const int* __restrict__ gh,
                                              int* __restrict__ jlist, int N){
  const int p = blockIdx.x * 256 + threadIdx.x;
  if (p >= N) return;
  const int4 cr = *reinterpret_cast<const int4*>(coords + (size_t)p * 4);
  const int b = cr.x, x = cr.y, y = cr.z, z = cr.w;
  int j[27];
  #pragma unroll
  for (int k = 0; k < 27; k++){
    const int dx = k / 9 - 1, dy = (k / 3) % 3 - 1, dz = k % 3 - 1;
    const int nx = x + dx, ny = y + dy, nz = z + dz;
    const bool ok = ((unsigned)nx < 128u) & ((unsigned)ny < 128u) & ((unsigned)nz < 128u);
    const int gi = ((((b << 7) + (nx & 127)) << 7) + (ny & 127)) * GRIDD + (nz & 127);
    const int jj = gh[gi];          // always in-range; 27 independent loads pipeline
    j[k] = ok ? jj : -1;
  }
  #pragma unroll
  for (int k = 0; k < 27; k++) jlist[(size_t)k * N + p] = j[k];
}

// ---------- phase 2: MFMA conv from jlist, fused BN stats, bf16 out ----------
__global__ __launch_bounds__(256) void convgemm(
    const unsigned short* __restrict__ F, const unsigned short* __restrict__ Wt,
    const int* __restrict__ jlist, unsigned short* __restrict__ Xm,
    float* __restrict__ gsum, float* __restrict__ gsq, int N)
{
  const int tid = threadIdx.x;
  const int wave = tid >> 6, lane = tid & 63;
  const int rbase = blockIdx.x * 64 + wave * 16;
  const int lo = lane & 15, hi = lane >> 4;
  const int p = rbase + lo;
  const int pc = p < N ? p : N - 1;
  int jl[27];
  #pragma unroll
  for (int k = 0; k < 27; k++){
    const int j = jlist[(size_t)k * N + pc];
    jl[k] = (p < N) ? j : -1;
  }
  floatx4 acc[8];
  #pragma unroll
  for (int i = 0; i < 8; i++) acc[i] = (floatx4){0.f, 0.f, 0.f, 0.f};

  for (int k = 0; k < 27; k++){
    if (__ballot(jl[k] >= 0) != 0ull){
      const int jc = jl[k] < 0 ? 0 : jl[k];
      const unsigned short* frow = F + (size_t)jc * C;
      const unsigned short* wb = Wt + (size_t)k * C * C;
      #pragma unroll
      for (int kc = 0; kc < 4; kc++){
        const int koff = kc * 32 + hi * 8;
        short8 a = *reinterpret_cast<const short8*>(frow + koff);
        if (jl[k] < 0) a = (short8){0,0,0,0,0,0,0,0};
        #pragma unroll
        for (int ct = 0; ct < 8; ct++){
          const short8 bf = *reinterpret_cast<const short8*>(wb + (size_t)(ct*16 + lo)*C + koff);
          acc[ct] = __builtin_amdgcn_mfma_f32_16x16x32_bf16(a, bf, acc[ct], 0, 0, 0);
        }
      }
    }
  }
  // epilogue: bf16 store + per-block column stats -> global atomics
  __shared__ float csum[128], csq[128];
  if (tid < 128){ csum[tid] = 0.f; csq[tid] = 0.f; }
  __syncthreads();
  #pragma unroll
  for (int ct = 0; ct < 8; ct++){
    const int col = ct * 16 + lo;
    float s = 0.f, q = 0.f;
    #pragma unroll
    for (int i2 = 0; i2 < 4; i2++){
      const int row = rbase + hi * 4 + i2;
      if (row < N){
        const float v = acc[ct][i2];
        Xm[(size_t)row * C + col] = f2bf(v);
        s += v; q += v * v;
      }
    }
    atomicAdd(&csum[col], s);
    atomicAdd(&csq[col], q);
  }
  __syncthreads();
  if (tid < 128){
    atomicAdd(&gsum[tid], csum[tid]);
    atomicAdd(&gsq[tid], csq[tid]);
  }
}

// ---------- per-(batch,slot) softmax denominator + wexp store ----------
__global__ __launch_bounds__(256) void denomk(const float* __restrict__ probs,
                                              const int* __restrict__ coords,
                                              float* __restrict__ denom,
                                              float* __restrict__ wexp, int N){
  const int k = threadIdx.x & 31, rh = threadIdx.x >> 5;
  float a0 = 0.f, a1 = 0.f, a2 = 0.f, a3 = 0.f;
  for (int r = blockIdx.x * 8 + rh; r < N; r += gridDim.x * 8){
    const int b = coords[(size_t)r * 4];
    const float e = __expf(probs[(size_t)r * 32 + k]);
    wexp[(size_t)r * 32 + k] = e;
    a0 += (b == 0) ? e : 0.f;
    a1 += (b == 1) ? e : 0.f;
    a2 += (b == 2) ? e : 0.f;
    a3 += (b == 3) ? e : 0.f;
  }
  if (a0 != 0.f) atomicAdd(&denom[0*32 + k], a0);
  if (a1 != 0.f) atomicAdd(&denom[1*32 + k], a1);
  if (a2 != 0.f) atomicAdd(&denom[2*32 + k], a2);
  if (a3 != 0.f) atomicAdd(&denom[3*32 + k], a3);
}

// ---------- finalize BN scale/shift + inverse denominators ----------
__global__ void finalizek(const float* __restrict__ sums, const float* __restrict__ sumsq,
                          const float* __restrict__ gamma, const float* __restrict__ beta,
                          const float* __restrict__ denom,
                          float* __restrict__ scalev, float* __restrict__ shiftv,
                          float* __restrict__ invden, int N){
  const int t = threadIdx.x;   // 128
  const float invN = 1.f / (float)N;
  const float mu = sums[t] * invN;
  const float var = sumsq[t] * invN - mu * mu;
  const float sc = gamma[t] * rsqrtf(var + 1e-5f);
  scalev[t] = sc;
  shiftv[t] = beta[t] - mu * sc;
  invden[t] = 1.f / denom[t];
}

// ---------- ctx partials with inline BN+ReLU ----------
__global__ __launch_bounds__(256) void ctx2k(const unsigned short* __restrict__ Xm,
                                             const float* __restrict__ wexp,
                                             const float* __restrict__ scalev,
                                             const float* __restrict__ shiftv,
                                             float* __restrict__ pbuf, int NPER){
  const int blk = blockIdx.x;
  const int b = blk >> 7, j = blk & 127;
  const int rows = (NPER + CTX_BPB - 1) / CTX_BPB;
  const int r0 = j * rows;
  const int r1 = min(r0 + rows, NPER);
  const int t = threadIdx.x, c = t & 127, rh = t >> 7;
  const float sc = scalev[c], sh = shiftv[c];
  float acc[KSLOT];
  #pragma unroll
  for (int k = 0; k < KSLOT; k++) acc[k] = 0.f;
  for (int r = r0 + rh; r < r1; r += 2){
    const size_t nn = (size_t)b * NPER + r;
    const float xv = fmaxf(fmaf(bf2f(Xm[nn * C + c]), sc, sh), 0.f);
    const float4* wr = reinterpret_cast<const float4*>(wexp + nn * KSLOT);
    #pragma unroll
    for (int kq = 0; kq < 8; kq++){
      const float4 w4 = wr[kq];
      acc[kq*4+0] = fmaf(w4.x, xv, acc[kq*4+0]);
      acc[kq*4+1] = fmaf(w4.y, xv, acc[kq*4+1]);
      acc[kq*4+2] = fmaf(w4.z, xv, acc[kq*4+2]);
      acc[kq*4+3] = fmaf(w4.w, xv, acc[kq*4+3]);
    }
  }
  __shared__ float red[2 * KSLOT * C];
  #pragma unroll
  for (int k = 0; k < KSLOT; k++) red[(rh * KSLOT + k) * C + c] = acc[k];
  __syncthreads();
  float* dst = pbuf + (size_t)blk * KSLOT * C;
  for (int i = t; i < KSLOT * C; i += 256) dst[i] = red[i] + red[KSLOT * C + i];
}

// ---------- kv: reduce ctx partials then project (coalesced bf16 weights) ----------
__global__ __launch_bounds__(256) void kvk(const float* __restrict__ pbuf,
                                           const float* __restrict__ invden,
                                           const unsigned short* __restrict__ WkvT,
                                           const float* __restrict__ inb,
                                           float* __restrict__ kh, float* __restrict__ vh){
  __shared__ float rowp[2][C];
  __shared__ float row[C];
  const int bk = blockIdx.x;              // b*32 + k
  const int b = bk >> 5, k = bk & 31;
  const int t = threadIdx.x, c = t & 127, jh = t >> 7;
  float s = 0.f;
  for (int j = jh; j < CTX_BPB; j += 2)
    s += pbuf[((size_t)(b * CTX_BPB + j) * KSLOT + k) * C + c];
  rowp[jh][c] = s;
  __syncthreads();
  if (t < C) row[t] = (rowp[0][t] + rowp[1][t]) * invden[b * KSLOT + k];
  __syncthreads();
  const int which = t >> 7;               // 0 -> K, 1 -> V
  const unsigned short* W = WkvT + (size_t)which * C * C;
  float acc = inb[(1 + which) * C + c];
  #pragma unroll 8
  for (int i = 0; i < C; i++) acc = fmaf(row[i], bf2f(W[i * C + c]), acc);
  (which ? vh : kh)[(size_t)bk * C + c] = acc;
}

// ---------- N x 128 @ (128x128)^T bf16 MFMA GEMM; optional inline BN on A ----------
__global__ __launch_bounds__(256) void gemm128(
    const unsigned short* __restrict__ A, const unsigned short* __restrict__ W,
    const float* __restrict__ bias,
    const float* __restrict__ bnsc, const float* __restrict__ bnsh,
    float scale, float* __restrict__ outF, unsigned short* __restrict__ outB, int N)
{
  const int tid = threadIdx.x;
  const int wave = tid >> 6, lane = tid & 63;
  const int rbase = blockIdx.x * 64 + (wave >> 1) * 32;
  const int cbase = (wave & 1) * 64;
  const int lo = lane & 15, hi = lane >> 4;
  floatx4 acc[2][4];
  #pragma unroll
  for (int rt = 0; rt < 2; rt++)
    #pragma unroll
    for (int ct = 0; ct < 4; ct++) acc[rt][ct] = (floatx4){0.f,0.f,0.f,0.f};
  const int m0 = rbase + lo, m1 = rbase + 16 + lo;
  const int m0c = m0 < N ? m0 : N - 1;
  const int m1c = m1 < N ? m1 : N - 1;
  #pragma unroll
  for (int kc = 0; kc < 4; kc++){
    const int koff = kc * 32 + hi * 8;
    short8 a0 = *reinterpret_cast<const short8*>(A + (size_t)m0c * C + koff);
    short8 a1 = *reinterpret_cast<const short8*>(A + (size_t)m1c * C + koff);
    if (bnsc){
      #pragma unroll
      for (int j = 0; j < 8; j++){
        const float scj = bnsc[koff + j], shj = bnsh[koff + j];
        a0[j] = (short)f2bf(fmaxf(fmaf(bf2f((unsigned short)a0[j]), scj, shj), 0.f));
        a1[j] = (short)f2bf(fmaxf(fmaf(bf2f((unsigned short)a1[j]), scj, shj), 0.f));
      }
    }
    #pragma unroll
    for (int ct = 0; ct < 4; ct++){
      const int n = cbase + ct * 16 + lo;
      const short8 b = *reinterpret_cast<const short8*>(W + (size_t)n * C + koff);
      acc[0][ct] = __builtin_amdgcn_mfma_f32_16x16x32_bf16(a0, b, acc[0][ct], 0, 0, 0);
      acc[1][ct] = __builtin_amdgcn_mfma_f32_16x16x32_bf16(a1, b, acc[1][ct], 0, 0, 0);
    }
  }
  #pragma unroll
  for (int rt = 0; rt < 2; rt++){
    #pragma unroll
    for (int ct = 0; ct < 4; ct++){
      const int col = cbase + ct * 16 + lo;
      const float bv = bias ? bias[col] : 0.f;
      #pragma unroll
      for (int i = 0; i < 4; i++){
        const int row = rbase + rt * 16 + hi * 4 + i;
        if (row < N){
          const float v = (acc[rt][ct][i] + bv) * scale;
          if (outF) outF[(size_t)row * C + col] = v;
          if (outB) outB[(size_t)row * C + col] = f2bf(v);
        }
      }
    }
  }
}

// ---------- attention v3: thread owns (row, head); P stays in registers ----------
__global__ __launch_bounds__(256) void attn3k(const unsigned short* __restrict__ qb,
                                              const float* __restrict__ kh,
                                              const float* __restrict__ vh,
                                              unsigned short* __restrict__ ob, int NPER){
  __shared__ float khL[KSLOT * C];
  __shared__ float vhL[KSLOT * C];
  const int t = threadIdx.x;
  const int b = blockIdx.y;
  const int n0 = blockIdx.x * 32;
  {
    const float4* ks = reinterpret_cast<const float4*>(kh + (size_t)b * KSLOT * C);
    const float4* vs = reinterpret_cast<const float4*>(vh + (size_t)b * KSLOT * C);
    float4* kd = reinterpret_cast<float4*>(khL);
    float4* vd = reinterpret_cast<float4*>(vhL);
    #pragma unroll
    for (int i = 0; i < 4; i++){ kd[i * 256 + t] = ks[i * 256 + t]; vd[i * 256 + t] = vs[i * 256 + t]; }
  }
  __syncthreads();
  const int h = t >> 5, p = t & 31;
  const int n = n0 + p;
  const int nc = n < NPER ? n : NPER - 1;
  float qv[16];
  {
    const short8* qp = reinterpret_cast<const short8*>(qb + ((size_t)b * NPER + nc) * C + h * 16);
    const short8 qa = qp[0], qc = qp[1];
    #pragma unroll
    for (int i = 0; i < 8; i++){
      qv[i]     = bf2f((unsigned short)qa[i]);
      qv[8 + i] = bf2f((unsigned short)qc[i]);
    }
  }
  float sv[KSLOT];
  #pragma unroll
  for (int k = 0; k < KSLOT; k++){
    const float4* kp = reinterpret_cast<const float4*>(&khL[k * C + h * 16]);
    const float4 k0 = kp[0], k1 = kp[1], k2 = kp[2], k3 = kp[3];
    float s;
    s = qv[0] * k0.x;
    s = fmaf(qv[1], k0.y, s);  s = fmaf(qv[2],  k0.z, s);  s = fmaf(qv[3],  k0.w, s);
    s = fmaf(qv[4], k1.x, s);  s = fmaf(qv[5],  k1.y, s);  s = fmaf(qv[6],  k1.z, s);
    s = fmaf(qv[7], k1.w, s);  s = fmaf(qv[8],  k2.x, s);  s = fmaf(qv[9],  k2.y, s);
    s = fmaf(qv[10], k2.z, s); s = fmaf(qv[11], k2.w, s);  s = fmaf(qv[12], k3.x, s);
    s = fmaf(qv[13], k3.y, s); s = fmaf(qv[14], k3.z, s);  s = fmaf(qv[15], k3.w, s);
    sv[k] = s;
  }
  float m = sv[0];
  #pragma unroll
  for (int k = 1; k < KSLOT; k++) m = fmaxf(m, sv[k]);
  float sum = 0.f;
  #pragma unroll
  for (int k = 0; k < KSLOT; k++){ const float e = __expf(sv[k] - m); sv[k] = e; sum += e; }
  const float inv = 1.f / sum;
  float o[16];
  #pragma unroll
  for (int i = 0; i < 16; i++) o[i] = 0.f;
  #pragma unroll
  for (int k = 0; k < KSLOT; k++){
    const float w = sv[k];
    const float4* vp = reinterpret_cast<const float4*>(&vhL[k * C + h * 16]);
    const float4 v0 = vp[0], v1 = vp[1], v2 = vp[2], v3 = vp[3];
    o[0]  = fmaf(w, v0.x, o[0]);  o[1]  = fmaf(w, v0.y, o[1]);
    o[2]  = fmaf(w, v0.z, o[2]);  o[3]  = fmaf(w, v0.w, o[3]);
    o[4]  = fmaf(w, v1.x, o[4]);  o[5]  = fmaf(w, v1.y, o[5]);
    o[6]  = fmaf(w, v1.z, o[6]);  o[7]  = fmaf(w, v1.w, o[7]);
    o[8]  = fmaf(w, v2.x, o[8]);  o[9]  = fmaf(w, v2.y, o[9]);
    o[10] = fmaf(w, v2.z, o[10]); o[11] = fmaf(w, v2.w, o[11]);
    o[12] = fmaf(w, v3.x, o[12]); o[13] = fmaf(w, v3.y, o[13]);
    o[14] = fmaf(w, v3.z, o[14]); o[15] = fmaf(w, v3.w, o[15]);
  }
  if (n < NPER){
    short8 s0, s1;
    #pragma unroll
    for (int i = 0; i < 8; i++){
      s0[i] = (short)f2bf(o[i] * inv);
      s1[i] = (short)f2bf(o[8 + i] * inv);
    }
    unsigned short* op = ob + ((size_t)b * NPER + n) * C + h * 16;
    *reinterpret_cast<short8*>(op) = s0;
    *reinterpret_cast<short8*>(op + 8) = s1;
  }
}

extern "C" void kernel_launch(void* const* d_in, const int* in_sizes, int n_in,
                              void* d_out, int out_size, void* d_ws, size_t ws_size,
                              hipStream_t stream){
  const float* feats  = (const float*)d_in[0];
  const float* probs  = (const float*)d_in[1];
  const float* convw  = (const float*)d_in[2];
  const float* gamma  = (const float*)d_in[3];
  const float* beta   = (const float*)d_in[4];
  const float* inw    = (const float*)d_in[5];
  const float* inb    = (const float*)d_in[6];
  const float* outw   = (const float*)d_in[7];
  const float* outb   = (const float*)d_in[8];
  const float* bw     = (const float*)d_in[9];
  const int*   coords = (const int*)d_in[10];
  const int N = in_sizes[0] / C;
  const int NPER = N / NB;

  char* ws = (char*)d_ws;
  size_t off = 0;
  auto alloc = [&](size_t bytes) -> char* {
    char* r = ws + off; off += (bytes + 255) & ~(size_t)255; return r;
  };
  int* grid_h            = (int*)alloc((size_t)NB * GRID3 * 4);          // 33.5 MB
  unsigned short* featsb = (unsigned short*)alloc((size_t)N * C * 2);    // 25.6 MB
  unsigned short* convwt = (unsigned short*)alloc((size_t)27 * C * C * 2);
  unsigned short* wq     = (unsigned short*)alloc((size_t)C * C * 2);
  unsigned short* wkvT   = (unsigned short*)alloc((size_t)2 * C * C * 2);
  unsigned short* w2b    = (unsigned short*)alloc((size_t)C * C * 2);
  float* b2              = (float*)alloc(512);
  unsigned short* xmid   = (unsigned short*)alloc((size_t)N * C * 2);    // conv out bf16
  unsigned short* qb     = (unsigned short*)alloc((size_t)N * C * 2);
  int* jlist             = (int*)alloc((size_t)27 * N * 4);              // 10.8 MB
  float* zero_base       = (float*)alloc((size_t)384 * 4);
  float* gsum   = zero_base;
  float* gsq    = zero_base + 128;
  float* denom  = zero_base + 256;
  float* invden = (float*)alloc(512);
  float* scalev = (float*)alloc(512);
  float* shiftv = (float*)alloc(512);
  float* kh     = (float*)alloc((size_t)NB * KSLOT * C * 4);
  float* vh     = (float*)alloc((size_t)NB * KSLOT * C * 4);
  // aliases into dead regions:
  float* wexp = (float*)grid_h;                  // grid dead after jlistk (12.8 MB)
  float* pbuf = wexp + (size_t)N * KSLOT;        // +8.4 MB ctx partials
  unsigned short* o_bf = featsb;                 // feats_bf dead after convgemm

  const long total1 = (long)N * C;
  hipMemsetAsync(grid_h, 0xFF, (size_t)NB * GRID3 * 4, stream);
  hipMemsetAsync(zero_base, 0, (size_t)384 * 4, stream);
  prepk<<<2048, 256, 0, stream>>>(feats, convw, inw, featsb, convwt, wq, wkvT, total1);
  w2k<<<128, 128, 0, stream>>>(bw, outw, outb, w2b, b2);
  scatterk<<<(N + 255) / 256, 256, 0, stream>>>(coords, grid_h, N);
  jlistk<<<(N + 255) / 256, 256, 0, stream>>>(coords, grid_h, jlist, N);
  // grid_h dead; wexp/pbuf alias it
  denomk<<<1024, 256, 0, stream>>>(probs, coords, denom, wexp, N);
  convgemm<<<(N + 63) / 64, 256, 0, stream>>>(featsb, convwt, jlist, xmid, gsum, gsq, N);
  finalizek<<<1, 128, 0, stream>>>(gsum, gsq, gamma, beta, denom, scalev, shiftv, invden, N);
  ctx2k<<<NB * CTX_BPB, 256, 0, stream>>>(xmid, wexp, scalev, shiftv, pbuf, NPER);
  kvk<<<NB * KSLOT, 256, 0, stream>>>(pbuf, invden, wkvT, inb, kh, vh);
  gemm128<<<(N + 63) / 64, 256, 0, stream>>>(xmid, wq, inb, scalev, shiftv, 0.25f, nullptr, qb, N);
  dim3 agrid((NPER + 31) / 32, NB);
  attn3k<<<agrid, 256, 0, stream>>>(qb, kh, vh, o_bf, NPER);
  gemm128<<<(N + 63) / 64, 256, 0, stream>>>(o_bf, w2b, b2, nullptr, nullptr, 1.f, (float*)d_out, nullptr, N);
}

// Round 5
// 598.057 us; speedup vs baseline: 1.7726x; 1.7726x over previous
//
#include <hip/hip_runtime.h>
#include <hip/hip_bf16.h>

typedef __attribute__((ext_vector_type(8))) short short8;
typedef __attribute__((ext_vector_type(4))) float floatx4;

#define NB 4
#define GRIDD 128
#define GRID3 (128*128*128)
#define C 128
#define KSLOT 32
#define CTX_BPB 128
#define DEN_BLK 256

static __device__ __forceinline__ unsigned short f2bf(float f){
  unsigned u = __builtin_bit_cast(unsigned, f);
  unsigned r = (u + 0x7FFFu + ((u >> 16) & 1u)) >> 16;
  return (unsigned short)r;
}
static __device__ __forceinline__ float bf2f(unsigned short h){
  unsigned u = ((unsigned)h) << 16;
  return __builtin_bit_cast(float, u);
}

// ---------- prep: bf16 conversions + transposes ----------
__global__ void prepk(const float* __restrict__ feats, const float* __restrict__ convw,
                      const float* __restrict__ inw,
                      unsigned short* __restrict__ Fb, unsigned short* __restrict__ Wt,
                      unsigned short* __restrict__ Wq, unsigned short* __restrict__ WkvT,
                      long total1)
{
  const long stride = (long)gridDim.x * blockDim.x;
  const long i0 = (long)blockIdx.x * blockDim.x + threadIdx.x;
  const long q4 = total1 >> 2;
  const float4* f4 = reinterpret_cast<const float4*>(feats);
  ushort4* fb4 = reinterpret_cast<ushort4*>(Fb);
  for (long i = i0; i < q4; i += stride){
    const float4 v = f4[i];
    ushort4 o; o.x = f2bf(v.x); o.y = f2bf(v.y); o.z = f2bf(v.z); o.w = f2bf(v.w);
    fb4[i] = o;
  }
  for (long i = i0; i < 27L*C*C; i += stride){
    long k = i >> 14; long r = (i >> 7) & 127; long c = i & 127;
    Wt[i] = f2bf(convw[(k << 14) + (c << 7) + r]);
  }
  for (long i = i0; i < C*C; i += stride) Wq[i] = f2bf(inw[i]);
  for (long i = i0; i < 2L*C*C; i += stride){
    long which = i >> 14, rem = i & 16383, ii = rem >> 7, cout = rem & 127;
    WkvT[i] = f2bf(inw[((1 + which) << 14) + (cout << 7) + ii]);
  }
}

// ---------- fold W2 = (bw[:, :128]+bw[:, 128:]) @ outw ; b2 = Wcf @ outb ----------
__global__ __launch_bounds__(128) void w2k(const float* __restrict__ bw,
                                           const float* __restrict__ outw,
                                           const float* __restrict__ outb,
                                           unsigned short* __restrict__ W2b,
                                           float* __restrict__ b2){
  const int o = blockIdx.x, i = threadIdx.x;
  __shared__ float wcf[128];
  __shared__ float red[128];
  const float w_i = bw[(size_t)o*256 + i] + bw[(size_t)o*256 + 128 + i];
  wcf[i] = w_i;
  red[i] = w_i * outb[i];
  __syncthreads();
  float acc = 0.f;
  #pragma unroll 8
  for (int j = 0; j < 128; j++) acc = fmaf(wcf[j], outw[j*128 + i], acc);
  W2b[o*128 + i] = f2bf(acc);
  for (int s = 64; s > 0; s >>= 1){
    if (i < s) red[i] += red[i + s];
    __syncthreads();
  }
  if (i == 0) b2[o] = red[0];
}

// ---------- scatter active sites into dense grid hash ----------
__global__ void scatterk(const int* __restrict__ coords, int* __restrict__ gh, int N){
  int p = blockIdx.x * 256 + threadIdx.x;
  if (p < N){
    int4 cr = *reinterpret_cast<const int4*>(coords + (size_t)p * 4);
    gh[(((cr.x*GRIDD + cr.y)*GRIDD + cr.z)*GRIDD) + cr.w] = p;
  }
}

// ---------- phase 1: all 27 neighbor lookups per point, high MLP ----------
__global__ __launch_bounds__(256) void jlistk(const int* __restrict__ coords,
                                              const int* __restrict__ gh,
                                              int* __restrict__ jlist, int N){
  const int p = blockIdx.x * 256 + threadIdx.x;
  if (p >= N) return;
  const int4 cr = *reinterpret_cast<const int4*>(coords + (size_t)p * 4);
  const int b = cr.x, x = cr.y, y = cr.z, z = cr.w;
  int j[27];
  #pragma unroll
  for (int k = 0; k < 27; k++){
    const int dx = k / 9 - 1, dy = (k / 3) % 3 - 1, dz = k % 3 - 1;
    const int nx = x + dx, ny = y + dy, nz = z + dz;
    const bool ok = ((unsigned)nx < 128u) & ((unsigned)ny < 128u) & ((unsigned)nz < 128u);
    const int gi = ((((b << 7) + (nx & 127)) << 7) + (ny & 127)) * GRIDD + (nz & 127);
    const int jj = gh[gi];
    j[k] = ok ? jj : -1;
  }
  #pragma unroll
  for (int k = 0; k < 27; k++) jlist[(size_t)k * N + p] = j[k];
}

// ---------- phase 2: MFMA conv from jlist; BN-stat PARTIALS (no global atomics) ----------
__global__ __launch_bounds__(256) void convgemm(
    const unsigned short* __restrict__ F, const unsigned short* __restrict__ Wt,
    const int* __restrict__ jlist, unsigned short* __restrict__ Xm,
    float* __restrict__ pgs, int N)
{
  const int tid = threadIdx.x;
  const int wave = tid >> 6, lane = tid & 63;
  const int rbase = blockIdx.x * 64 + wave * 16;
  const int lo = lane & 15, hi = lane >> 4;
  const int p = rbase + lo;
  const int pc = p < N ? p : N - 1;
  int jl[27];
  #pragma unroll
  for (int k = 0; k < 27; k++){
    const int j = jlist[(size_t)k * N + pc];
    jl[k] = (p < N) ? j : -1;
  }
  floatx4 acc[8];
  #pragma unroll
  for (int i = 0; i < 8; i++) acc[i] = (floatx4){0.f, 0.f, 0.f, 0.f};

  for (int k = 0; k < 27; k++){
    if (__ballot(jl[k] >= 0) != 0ull){
      const int jc = jl[k] < 0 ? 0 : jl[k];
      const unsigned short* frow = F + (size_t)jc * C;
      const unsigned short* wb = Wt + (size_t)k * C * C;
      #pragma unroll
      for (int kc = 0; kc < 4; kc++){
        const int koff = kc * 32 + hi * 8;
        short8 a = *reinterpret_cast<const short8*>(frow + koff);
        if (jl[k] < 0) a = (short8){0,0,0,0,0,0,0,0};
        #pragma unroll
        for (int ct = 0; ct < 8; ct++){
          const short8 bf = *reinterpret_cast<const short8*>(wb + (size_t)(ct*16 + lo)*C + koff);
          acc[ct] = __builtin_amdgcn_mfma_f32_16x16x32_bf16(a, bf, acc[ct], 0, 0, 0);
        }
      }
    }
  }
  __shared__ float csum[128], csq[128];
  if (tid < 128){ csum[tid] = 0.f; csq[tid] = 0.f; }
  __syncthreads();
  #pragma unroll
  for (int ct = 0; ct < 8; ct++){
    const int col = ct * 16 + lo;
    float s = 0.f, q = 0.f;
    #pragma unroll
    for (int i2 = 0; i2 < 4; i2++){
      const int row = rbase + hi * 4 + i2;
      if (row < N){
        const float v = acc[ct][i2];
        Xm[(size_t)row * C + col] = f2bf(v);
        s += v; q += v * v;
      }
    }
    atomicAdd(&csum[col], s);
    atomicAdd(&csq[col], q);
  }
  __syncthreads();
  pgs[(size_t)blockIdx.x * 256 + tid] = (tid < 128) ? csum[tid] : csq[tid - 128];
}

// ---------- denom partials + wexp (no global atomics) ----------
__global__ __launch_bounds__(256) void denomk(const float* __restrict__ probs,
                                              const int* __restrict__ coords,
                                              float* __restrict__ dpart,
                                              float* __restrict__ wexp, int N){
  const int t = threadIdx.x, k = t & 31, rh = t >> 5;
  float a0 = 0.f, a1 = 0.f, a2 = 0.f, a3 = 0.f;
  for (int r = blockIdx.x * 8 + rh; r < N; r += DEN_BLK * 8){
    const int b = coords[(size_t)r * 4];
    const float e = __expf(probs[(size_t)r * 32 + k]);
    wexp[(size_t)r * 32 + k] = e;
    a0 += (b == 0) ? e : 0.f;
    a1 += (b == 1) ? e : 0.f;
    a2 += (b == 2) ? e : 0.f;
    a3 += (b == 3) ? e : 0.f;
  }
  __shared__ float ls[8][128];
  ls[rh][0*32 + k] = a0; ls[rh][1*32 + k] = a1;
  ls[rh][2*32 + k] = a2; ls[rh][3*32 + k] = a3;
  __syncthreads();
  if (t < 128){
    float s = 0.f;
    #pragma unroll
    for (int j = 0; j < 8; j++) s += ls[j][t];
    dpart[(size_t)blockIdx.x * 128 + t] = s;
  }
}

// ---------- reduce partials: which=0 gsum, 1 gsq, 2 denom ----------
__global__ __launch_bounds__(128) void reduk(const float* __restrict__ pgs, int nblk,
                                             const float* __restrict__ dpart,
                                             float* __restrict__ gsum,
                                             float* __restrict__ gsq,
                                             float* __restrict__ denom){
  const int which = blockIdx.x, slice = blockIdx.y, t = threadIdx.x;
  float s = 0.f;
  if (which < 2){
    const float* src = pgs + which * 128 + t;
    for (int j = slice; j < nblk; j += 8) s += src[(size_t)j * 256];
    atomicAdd((which ? gsq : gsum) + t, s);
  } else {
    const float* src = dpart + t;
    for (int j = slice; j < DEN_BLK; j += 8) s += src[(size_t)j * 128];
    atomicAdd(denom + t, s);
  }
}

// ---------- finalize BN scale/shift + inverse denominators ----------
__global__ void finalizek(const float* __restrict__ sums, const float* __restrict__ sumsq,
                          const float* __restrict__ gamma, const float* __restrict__ beta,
                          const float* __restrict__ denom,
                          float* __restrict__ scalev, float* __restrict__ shiftv,
                          float* __restrict__ invden, int N){
  const int t = threadIdx.x;   // 128
  const float invN = 1.f / (float)N;
  const float mu = sums[t] * invN;
  const float var = sumsq[t] * invN - mu * mu;
  const float sc = gamma[t] * rsqrtf(var + 1e-5f);
  scalev[t] = sc;
  shiftv[t] = beta[t] - mu * sc;
  invden[t] = 1.f / denom[t];
}

// ---------- ctx partials with inline BN+ReLU ----------
__global__ __launch_bounds__(256) void ctx2k(const unsigned short* __restrict__ Xm,
                                             const float* __restrict__ wexp,
                                             const float* __restrict__ scalev,
                                             const float* __restrict__ shiftv,
                                             float* __restrict__ pbuf, int NPER){
  const int blk = blockIdx.x;
  const int b = blk >> 7, j = blk & 127;
  const int rows = (NPER + CTX_BPB - 1) / CTX_BPB;
  const int r0 = j * rows;
  const int r1 = min(r0 + rows, NPER);
  const int t = threadIdx.x, c = t & 127, rh = t >> 7;
  const float sc = scalev[c], sh = shiftv[c];
  float acc[KSLOT];
  #pragma unroll
  for (int k = 0; k < KSLOT; k++) acc[k] = 0.f;
  for (int r = r0 + rh; r < r1; r += 2){
    const size_t nn = (size_t)b * NPER + r;
    const float xv = fmaxf(fmaf(bf2f(Xm[nn * C + c]), sc, sh), 0.f);
    const float4* wr = reinterpret_cast<const float4*>(wexp + nn * KSLOT);
    #pragma unroll
    for (int kq = 0; kq < 8; kq++){
      const float4 w4 = wr[kq];
      acc[kq*4+0] = fmaf(w4.x, xv, acc[kq*4+0]);
      acc[kq*4+1] = fmaf(w4.y, xv, acc[kq*4+1]);
      acc[kq*4+2] = fmaf(w4.z, xv, acc[kq*4+2]);
      acc[kq*4+3] = fmaf(w4.w, xv, acc[kq*4+3]);
    }
  }
  __shared__ float red[2 * KSLOT * C];
  #pragma unroll
  for (int k = 0; k < KSLOT; k++) red[(rh * KSLOT + k) * C + c] = acc[k];
  __syncthreads();
  float* dst = pbuf + (size_t)blk * KSLOT * C;
  for (int i = t; i < KSLOT * C; i += 256) dst[i] = red[i] + red[KSLOT * C + i];
}

// ---------- kv: reduce ctx partials then project ----------
__global__ __launch_bounds__(256) void kvk(const float* __restrict__ pbuf,
                                           const float* __restrict__ invden,
                                           const unsigned short* __restrict__ WkvT,
                                           const float* __restrict__ inb,
                                           float* __restrict__ kh, float* __restrict__ vh){
  __shared__ float rowp[2][C];
  __shared__ float row[C];
  const int bk = blockIdx.x;              // b*32 + k
  const int b = bk >> 5, k = bk & 31;
  const int t = threadIdx.x, c = t & 127, jh = t >> 7;
  float s = 0.f;
  for (int j = jh; j < CTX_BPB; j += 2)
    s += pbuf[((size_t)(b * CTX_BPB + j) * KSLOT + k) * C + c];
  rowp[jh][c] = s;
  __syncthreads();
  if (t < C) row[t] = (rowp[0][t] + rowp[1][t]) * invden[b * KSLOT + k];
  __syncthreads();
  const int which = t >> 7;               // 0 -> K, 1 -> V
  const unsigned short* W = WkvT + (size_t)which * C * C;
  float acc = inb[(1 + which) * C + c];
  #pragma unroll 8
  for (int i = 0; i < C; i++) acc = fmaf(row[i], bf2f(W[i * C + c]), acc);
  (which ? vh : kh)[(size_t)bk * C + c] = acc;
}

// ---------- N x 128 @ (128x128)^T bf16 MFMA GEMM; optional inline BN on A ----------
__global__ __launch_bounds__(256) void gemm128(
    const unsigned short* __restrict__ A, const unsigned short* __restrict__ W,
    const float* __restrict__ bias,
    const float* __restrict__ bnsc, const float* __restrict__ bnsh,
    float scale, float* __restrict__ outF, unsigned short* __restrict__ outB, int N)
{
  const int tid = threadIdx.x;
  const int wave = tid >> 6, lane = tid & 63;
  const int rbase = blockIdx.x * 64 + (wave >> 1) * 32;
  const int cbase = (wave & 1) * 64;
  const int lo = lane & 15, hi = lane >> 4;
  floatx4 acc[2][4];
  #pragma unroll
  for (int rt = 0; rt < 2; rt++)
    #pragma unroll
    for (int ct = 0; ct < 4; ct++) acc[rt][ct] = (floatx4){0.f,0.f,0.f,0.f};
  const int m0 = rbase + lo, m1 = rbase + 16 + lo;
  const int m0c = m0 < N ? m0 : N - 1;
  const int m1c = m1 < N ? m1 : N - 1;
  #pragma unroll
  for (int kc = 0; kc < 4; kc++){
    const int koff = kc * 32 + hi * 8;
    short8 a0 = *reinterpret_cast<const short8*>(A + (size_t)m0c * C + koff);
    short8 a1 = *reinterpret_cast<const short8*>(A + (size_t)m1c * C + koff);
    if (bnsc){
      #pragma unroll
      for (int j = 0; j < 8; j++){
        const float scj = bnsc[koff + j], shj = bnsh[koff + j];
        a0[j] = (short)f2bf(fmaxf(fmaf(bf2f((unsigned short)a0[j]), scj, shj), 0.f));
        a1[j] = (short)f2bf(fmaxf(fmaf(bf2f((unsigned short)a1[j]), scj, shj), 0.f));
      }
    }
    #pragma unroll
    for (int ct = 0; ct < 4; ct++){
      const int n = cbase + ct * 16 + lo;
      const short8 b = *reinterpret_cast<const short8*>(W + (size_t)n * C + koff);
      acc[0][ct] = __builtin_amdgcn_mfma_f32_16x16x32_bf16(a0, b, acc[0][ct], 0, 0, 0);
      acc[1][ct] = __builtin_amdgcn_mfma_f32_16x16x32_bf16(a1, b, acc[1][ct], 0, 0, 0);
    }
  }
  #pragma unroll
  for (int rt = 0; rt < 2; rt++){
    #pragma unroll
    for (int ct = 0; ct < 4; ct++){
      const int col = cbase + ct * 16 + lo;
      const float bv = bias ? bias[col] : 0.f;
      #pragma unroll
      for (int i = 0; i < 4; i++){
        const int row = rbase + rt * 16 + hi * 4 + i;
        if (row < N){
          const float v = (acc[rt][ct][i] + bv) * scale;
          if (outF) outF[(size_t)row * C + col] = v;
          if (outB) outB[(size_t)row * C + col] = f2bf(v);
        }
      }
    }
  }
}

// ---------- attention v3: thread owns (row, head); P stays in registers ----------
__global__ __launch_bounds__(256) void attn3k(const unsigned short* __restrict__ qb,
                                              const float* __restrict__ kh,
                                              const float* __restrict__ vh,
                                              unsigned short* __restrict__ ob, int NPER){
  __shared__ float khL[KSLOT * C];
  __shared__ float vhL[KSLOT * C];
  const int t = threadIdx.x;
  const int b = blockIdx.y;
  const int n0 = blockIdx.x * 32;
  {
    const float4* ks = reinterpret_cast<const float4*>(kh + (size_t)b * KSLOT * C);
    const float4* vs = reinterpret_cast<const float4*>(vh + (size_t)b * KSLOT * C);
    float4* kd = reinterpret_cast<float4*>(khL);
    float4* vd = reinterpret_cast<float4*>(vhL);
    #pragma unroll
    for (int i = 0; i < 4; i++){ kd[i * 256 + t] = ks[i * 256 + t]; vd[i * 256 + t] = vs[i * 256 + t]; }
  }
  __syncthreads();
  const int h = t >> 5, p = t & 31;
  const int n = n0 + p;
  const int nc = n < NPER ? n : NPER - 1;
  float qv[16];
  {
    const short8* qp = reinterpret_cast<const short8*>(qb + ((size_t)b * NPER + nc) * C + h * 16);
    const short8 qa = qp[0], qc = qp[1];
    #pragma unroll
    for (int i = 0; i < 8; i++){
      qv[i]     = bf2f((unsigned short)qa[i]);
      qv[8 + i] = bf2f((unsigned short)qc[i]);
    }
  }
  float sv[KSLOT];
  #pragma unroll
  for (int k = 0; k < KSLOT; k++){
    const float4* kp = reinterpret_cast<const float4*>(&khL[k * C + h * 16]);
    const float4 k0 = kp[0], k1 = kp[1], k2 = kp[2], k3 = kp[3];
    float s;
    s = qv[0] * k0.x;
    s = fmaf(qv[1], k0.y, s);  s = fmaf(qv[2],  k0.z, s);  s = fmaf(qv[3],  k0.w, s);
    s = fmaf(qv[4], k1.x, s);  s = fmaf(qv[5],  k1.y, s);  s = fmaf(qv[6],  k1.z, s);
    s = fmaf(qv[7], k1.w, s);  s = fmaf(qv[8],  k2.x, s);  s = fmaf(qv[9],  k2.y, s);
    s = fmaf(qv[10], k2.z, s); s = fmaf(qv[11], k2.w, s);  s = fmaf(qv[12], k3.x, s);
    s = fmaf(qv[13], k3.y, s); s = fmaf(qv[14], k3.z, s);  s = fmaf(qv[15], k3.w, s);
    sv[k] = s;
  }
  float m = sv[0];
  #pragma unroll
  for (int k = 1; k < KSLOT; k++) m = fmaxf(m, sv[k]);
  float sum = 0.f;
  #pragma unroll
  for (int k = 0; k < KSLOT; k++){ const float e = __expf(sv[k] - m); sv[k] = e; sum += e; }
  const float inv = 1.f / sum;
  float o[16];
  #pragma unroll
  for (int i = 0; i < 16; i++) o[i] = 0.f;
  #pragma unroll
  for (int k = 0; k < KSLOT; k++){
    const float w = sv[k];
    const float4* vp = reinterpret_cast<const float4*>(&vhL[k * C + h * 16]);
    const float4 v0 = vp[0], v1 = vp[1], v2 = vp[2], v3 = vp[3];
    o[0]  = fmaf(w, v0.x, o[0]);  o[1]  = fmaf(w, v0.y, o[1]);
    o[2]  = fmaf(w, v0.z, o[2]);  o[3]  = fmaf(w, v0.w, o[3]);
    o[4]  = fmaf(w, v1.x, o[4]);  o[5]  = fmaf(w, v1.y, o[5]);
    o[6]  = fmaf(w, v1.z, o[6]);  o[7]  = fmaf(w, v1.w, o[7]);
    o[8]  = fmaf(w, v2.x, o[8]);  o[9]  = fmaf(w, v2.y, o[9]);
    o[10] = fmaf(w, v2.z, o[10]); o[11] = fmaf(w, v2.w, o[11]);
    o[12] = fmaf(w, v3.x, o[12]); o[13] = fmaf(w, v3.y, o[13]);
    o[14] = fmaf(w, v3.z, o[14]); o[15] = fmaf(w, v3.w, o[15]);
  }
  if (n < NPER){
    short8 s0, s1;
    #pragma unroll
    for (int i = 0; i < 8; i++){
      s0[i] = (short)f2bf(o[i] * inv);
      s1[i] = (short)f2bf(o[8 + i] * inv);
    }
    unsigned short* op = ob + ((size_t)b * NPER + n) * C + h * 16;
    *reinterpret_cast<short8*>(op) = s0;
    *reinterpret_cast<short8*>(op + 8) = s1;
  }
}

extern "C" void kernel_launch(void* const* d_in, const int* in_sizes, int n_in,
                              void* d_out, int out_size, void* d_ws, size_t ws_size,
                              hipStream_t stream){
  const float* feats  = (const float*)d_in[0];
  const float* probs  = (const float*)d_in[1];
  const float* convw  = (const float*)d_in[2];
  const float* gamma  = (const float*)d_in[3];
  const float* beta   = (const float*)d_in[4];
  const float* inw    = (const float*)d_in[5];
  const float* inb    = (const float*)d_in[6];
  const float* outw   = (const float*)d_in[7];
  const float* outb   = (const float*)d_in[8];
  const float* bw     = (const float*)d_in[9];
  const int*   coords = (const int*)d_in[10];
  const int N = in_sizes[0] / C;
  const int NPER = N / NB;
  const int NBLK = (N + 63) / 64;

  char* ws = (char*)d_ws;
  size_t off = 0;
  auto alloc = [&](size_t bytes) -> char* {
    char* r = ws + off; off += (bytes + 255) & ~(size_t)255; return r;
  };
  int* grid_h            = (int*)alloc((size_t)NB * GRID3 * 4);          // 33.5 MB
  unsigned short* featsb = (unsigned short*)alloc((size_t)N * C * 2);
  unsigned short* convwt = (unsigned short*)alloc((size_t)27 * C * C * 2);
  unsigned short* wq     = (unsigned short*)alloc((size_t)C * C * 2);
  unsigned short* wkvT   = (unsigned short*)alloc((size_t)2 * C * C * 2);
  unsigned short* w2b    = (unsigned short*)alloc((size_t)C * C * 2);
  float* b2              = (float*)alloc(512);
  unsigned short* xmid   = (unsigned short*)alloc((size_t)N * C * 2);
  unsigned short* qb     = (unsigned short*)alloc((size_t)N * C * 2);
  int* jlist             = (int*)alloc((size_t)27 * N * 4);
  float* pgs             = (float*)alloc((size_t)NBLK * 256 * 4);        // conv stat partials
  float* dpart           = (float*)alloc((size_t)DEN_BLK * 128 * 4);     // denom partials
  float* zero_base       = (float*)alloc((size_t)384 * 4);
  float* gsum   = zero_base;
  float* gsq    = zero_base + 128;
  float* denom  = zero_base + 256;
  float* invden = (float*)alloc(512);
  float* scalev = (float*)alloc(512);
  float* shiftv = (float*)alloc(512);
  float* kh     = (float*)alloc((size_t)NB * KSLOT * C * 4);
  float* vh     = (float*)alloc((size_t)NB * KSLOT * C * 4);
  // aliases into dead regions:
  float* wexp = (float*)grid_h;                  // grid dead after jlistk (12.8 MB)
  float* pbuf = wexp + (size_t)N * KSLOT;        // +8.4 MB ctx partials
  unsigned short* o_bf = featsb;                 // feats_bf dead after convgemm

  const long total1 = (long)N * C;
  hipMemsetAsync(grid_h, 0xFF, (size_t)NB * GRID3 * 4, stream);
  hipMemsetAsync(zero_base, 0, (size_t)384 * 4, stream);
  prepk<<<2048, 256, 0, stream>>>(feats, convw, inw, featsb, convwt, wq, wkvT, total1);
  w2k<<<128, 128, 0, stream>>>(bw, outw, outb, w2b, b2);
  scatterk<<<(N + 255) / 256, 256, 0, stream>>>(coords, grid_h, N);
  jlistk<<<(N + 255) / 256, 256, 0, stream>>>(coords, grid_h, jlist, N);
  // grid_h dead; wexp/pbuf alias it
  denomk<<<DEN_BLK, 256, 0, stream>>>(probs, coords, dpart, wexp, N);
  convgemm<<<NBLK, 256, 0, stream>>>(featsb, convwt, jlist, xmid, pgs, N);
  {
    dim3 rg(3, 8);
    reduk<<<rg, 128, 0, stream>>>(pgs, NBLK, dpart, gsum, gsq, denom);
  }
  finalizek<<<1, 128, 0, stream>>>(gsum, gsq, gamma, beta, denom, scalev, shiftv, invden, N);
  ctx2k<<<NB * CTX_BPB, 256, 0, stream>>>(xmid, wexp, scalev, shiftv, pbuf, NPER);
  kvk<<<NB * KSLOT, 256, 0, stream>>>(pbuf, invden, wkvT, inb, kh, vh);
  gemm128<<<NBLK, 256, 0, stream>>>(xmid, wq, inb, scalev, shiftv, 0.25f, nullptr, qb, N);
  dim3 agrid((NPER + 31) / 32, NB);
  attn3k<<<agrid, 256, 0, stream>>>(qb, kh, vh, o_bf, NPER);
  gemm128<<<NBLK, 256, 0, stream>>>(o_bf, w2b, b2, nullptr, nullptr, 1.f, (float*)d_out, nullptr, N);
}

// Round 7
// 486.906 us; speedup vs baseline: 2.1772x; 1.2283x over previous
//
#include <hip/hip_runtime.h>
#include <hip/hip_bf16.h>

typedef __attribute__((ext_vector_type(8))) short short8;
typedef __attribute__((ext_vector_type(4))) float floatx4;

#define NB 4
#define GRIDD 128
#define GRID3 (128*128*128)
#define C 128
#define KSLOT 32
#define CTX_BPB 128
#define DEN_BLK 256
#define PCAP 8192   // pair capacity per offset (expect ~1190, 200 sigma headroom)

static __device__ __forceinline__ unsigned short f2bf(float f){
  unsigned u = __builtin_bit_cast(unsigned, f);
  unsigned r = (u + 0x7FFFu + ((u >> 16) & 1u)) >> 16;
  return (unsigned short)r;
}
static __device__ __forceinline__ float bf2f(unsigned short h){
  unsigned u = ((unsigned)h) << 16;
  return __builtin_bit_cast(float, u);
}

// ---------- prep: bf16 conversions + transposes ----------
__global__ void prepk(const float* __restrict__ feats, const float* __restrict__ convw,
                      const float* __restrict__ inw,
                      unsigned short* __restrict__ Fb, unsigned short* __restrict__ Wt,
                      unsigned short* __restrict__ Wq, unsigned short* __restrict__ WkvT,
                      long total1)
{
  const long stride = (long)gridDim.x * blockDim.x;
  const long i0 = (long)blockIdx.x * blockDim.x + threadIdx.x;
  const long q4 = total1 >> 2;
  const float4* f4 = reinterpret_cast<const float4*>(feats);
  ushort4* fb4 = reinterpret_cast<ushort4*>(Fb);
  for (long i = i0; i < q4; i += stride){
    const float4 v = f4[i];
    ushort4 o; o.x = f2bf(v.x); o.y = f2bf(v.y); o.z = f2bf(v.z); o.w = f2bf(v.w);
    fb4[i] = o;
  }
  for (long i = i0; i < 27L*C*C; i += stride){
    long k = i >> 14; long r = (i >> 7) & 127; long c = i & 127;
    Wt[i] = f2bf(convw[(k << 14) + (c << 7) + r]);
  }
  for (long i = i0; i < C*C; i += stride) Wq[i] = f2bf(inw[i]);
  for (long i = i0; i < 2L*C*C; i += stride){
    long which = i >> 14, rem = i & 16383, ii = rem >> 7, cout = rem & 127;
    WkvT[i] = f2bf(inw[((1 + which) << 14) + (cout << 7) + ii]);
  }
}

// ---------- fold W2 = (bw[:, :128]+bw[:, 128:]) @ outw ; b2 = Wcf @ outb ----------
__global__ __launch_bounds__(128) void w2k(const float* __restrict__ bw,
                                           const float* __restrict__ outw,
                                           const float* __restrict__ outb,
                                           unsigned short* __restrict__ W2b,
                                           float* __restrict__ b2){
  const int o = blockIdx.x, i = threadIdx.x;
  __shared__ float wcf[128];
  __shared__ float red[128];
  const float w_i = bw[(size_t)o*256 + i] + bw[(size_t)o*256 + 128 + i];
  wcf[i] = w_i;
  red[i] = w_i * outb[i];
  __syncthreads();
  float acc = 0.f;
  #pragma unroll 8
  for (int j = 0; j < 128; j++) acc = fmaf(wcf[j], outw[j*128 + i], acc);
  W2b[o*128 + i] = f2bf(acc);
  for (int s = 64; s > 0; s >>= 1){
    if (i < s) red[i] += red[i + s];
    __syncthreads();
  }
  if (i == 0) b2[o] = red[0];
}

// ---------- scatter active sites into dense grid hash ----------
__global__ void scatterk(const int* __restrict__ coords, int* __restrict__ gh, int N){
  int p = blockIdx.x * 256 + threadIdx.x;
  if (p < N){
    int4 cr = *reinterpret_cast<const int4*>(coords + (size_t)p * 4);
    gh[(((cr.x*GRIDD + cr.y)*GRIDD + cr.z)*GRIDD) + cr.w] = p;
  }
}

// ---------- build compacted (i,j) pair lists per non-center offset ----------
__global__ __launch_bounds__(256) void pairk(const int* __restrict__ coords,
                                             const int* __restrict__ gh,
                                             int2* __restrict__ pairs,
                                             int* __restrict__ gcnt, int N){
  __shared__ int lcnt[27], lbase[27];
  const int t = threadIdx.x;
  if (t < 27) lcnt[t] = 0;
  __syncthreads();
  const int p = blockIdx.x * 256 + t;
  const bool active = p < N;
  int jl[27];
  if (active){
    const int4 cr = *reinterpret_cast<const int4*>(coords + (size_t)p * 4);
    const int b = cr.x, x = cr.y, y = cr.z, z = cr.w;
    #pragma unroll
    for (int k = 0; k < 27; k++){
      if (k == 13){ jl[k] = -1; continue; }
      const int dx = k / 9 - 1, dy = (k / 3) % 3 - 1, dz = k % 3 - 1;
      const int nx = x + dx, ny = y + dy, nz = z + dz;
      const bool ok = ((unsigned)nx < 128u) & ((unsigned)ny < 128u) & ((unsigned)nz < 128u);
      const int gi = ((((b << 7) + (nx & 127)) << 7) + (ny & 127)) * GRIDD + (nz & 127);
      const int jj = gh[gi];
      jl[k] = ok ? jj : -1;
      if (jl[k] >= 0) atomicAdd(&lcnt[k], 1);
    }
  }
  __syncthreads();
  if (t < 27 && t != 13 && lcnt[t] > 0) lbase[t] = atomicAdd(&gcnt[t], lcnt[t]);
  __syncthreads();
  if (t < 27) lcnt[t] = 0;
  __syncthreads();
  if (active){
    #pragma unroll
    for (int k = 0; k < 27; k++){
      if (k == 13) continue;
      if (jl[k] >= 0){
        const int slot = lbase[k] + atomicAdd(&lcnt[k], 1);
        if (slot < PCAP) pairs[(size_t)k * PCAP + slot] = make_int2(p, jl[k]);
      }
    }
  }
}

// ---------- off-center scatter-GEMM: Wt[k] in LDS, 16-pair chunks, atomic adds ----------
__global__ __launch_bounds__(256) void scatk(
    const unsigned short* __restrict__ F, const unsigned short* __restrict__ Wt,
    const int2* __restrict__ pairs, const int* __restrict__ gcnt,
    float* __restrict__ X, int N)
{
  __shared__ unsigned short wl[128 * 136];   // 136-short stride: 16B-aligned rows
  const int k = (blockIdx.x < 13) ? blockIdx.x : blockIdx.x + 1;  // skip center
  const int t = threadIdx.x;
  const unsigned short* wg = Wt + (size_t)k * C * C;
  for (int idx = t; idx < 128 * 16; idx += 256){
    const int row = idx >> 4, seg = idx & 15;
    *reinterpret_cast<short8*>(&wl[row * 136 + seg * 8]) =
        *reinterpret_cast<const short8*>(wg + row * 128 + seg * 8);
  }
  __syncthreads();
  const int cnt = min(gcnt[k], PCAP);
  const int nch = (cnt + 15) >> 4;
  const int wave = t >> 6, lane = t & 63, lo = lane & 15, hi = lane >> 4;
  for (int c = blockIdx.y * 4 + wave; c < nch; c += 32 * 4){
    const int pidx = c * 16 + lo;
    const bool pv = pidx < cnt;
    const int2 pr = pv ? pairs[(size_t)k * PCAP + pidx] : make_int2(0, 0);
    const unsigned short* frow = F + (size_t)pr.y * C;
    short8 a[4];
    #pragma unroll
    for (int kc = 0; kc < 4; kc++){
      a[kc] = *reinterpret_cast<const short8*>(frow + kc * 32 + hi * 8);
      if (!pv) a[kc] = (short8){0,0,0,0,0,0,0,0};
    }
    floatx4 acc[8];
    #pragma unroll
    for (int i = 0; i < 8; i++) acc[i] = (floatx4){0.f,0.f,0.f,0.f};
    #pragma unroll
    for (int kc = 0; kc < 4; kc++){
      const int koff = kc * 32 + hi * 8;
      #pragma unroll
      for (int ct = 0; ct < 8; ct++){
        const short8 b = *reinterpret_cast<const short8*>(&wl[(ct*16 + lo) * 136 + koff]);
        acc[ct] = __builtin_amdgcn_mfma_f32_16x16x32_bf16(a[kc], b, acc[ct], 0, 0, 0);
      }
    }
    #pragma unroll
    for (int i2 = 0; i2 < 4; i2++){
      const int src = hi * 4 + i2;
      const int row = __shfl(pr.x, src);      // lanes 0..15 hold pairs 0..15
      if (c * 16 + src < cnt){
        #pragma unroll
        for (int ct = 0; ct < 8; ct++)
          atomicAdd(&X[(size_t)row * C + ct * 16 + lo], acc[ct][i2]);
      }
    }
  }
}

// ---------- denom partials + wexp (no hot atomics) ----------
__global__ __launch_bounds__(256) void denomk(const float* __restrict__ probs,
                                              const int* __restrict__ coords,
                                              float* __restrict__ dpart,
                                              float* __restrict__ wexp, int N){
  const int t = threadIdx.x, k = t & 31, rh = t >> 5;
  float a0 = 0.f, a1 = 0.f, a2 = 0.f, a3 = 0.f;
  for (int r = blockIdx.x * 8 + rh; r < N; r += DEN_BLK * 8){
    const int b = coords[(size_t)r * 4];
    const float e = __expf(probs[(size_t)r * 32 + k]);
    wexp[(size_t)r * 32 + k] = e;
    a0 += (b == 0) ? e : 0.f;
    a1 += (b == 1) ? e : 0.f;
    a2 += (b == 2) ? e : 0.f;
    a3 += (b == 3) ? e : 0.f;
  }
  __shared__ float ls[8][128];
  ls[rh][0*32 + k] = a0; ls[rh][1*32 + k] = a1;
  ls[rh][2*32 + k] = a2; ls[rh][3*32 + k] = a3;
  __syncthreads();
  if (t < 128){
    float s = 0.f;
    #pragma unroll
    for (int j = 0; j < 8; j++) s += ls[j][t];
    dpart[(size_t)blockIdx.x * 128 + t] = s;
  }
}

// ---------- BN stat partials over f32 xconv ----------
__global__ __launch_bounds__(256) void statsk(const float* __restrict__ X,
                                              float* __restrict__ spgs, int N){
  const int t = threadIdx.x, c = t & 127, rh = t >> 7;
  float s = 0.f, s2 = 0.f;
  for (int r = blockIdx.x * 2 + rh; r < N; r += 512){
    const float v = X[(size_t)r * C + c];
    s += v; s2 += v * v;
  }
  __shared__ float ls[256], ls2[256];
  ls[t] = s; ls2[t] = s2;
  __syncthreads();
  spgs[(size_t)blockIdx.x * 256 + t] =
      (t < 128) ? (ls[t] + ls[t + 128]) : (ls2[t - 128] + ls2[t]);
}

// ---------- reduce partials: which=0 gsum, 1 gsq, 2 denom ----------
__global__ __launch_bounds__(128) void reduk(const float* __restrict__ pgs, int nblk,
                                             const float* __restrict__ dpart,
                                             float* __restrict__ gsum,
                                             float* __restrict__ gsq,
                                             float* __restrict__ denom){
  const int which = blockIdx.x, slice = blockIdx.y, t = threadIdx.x;
  float s = 0.f;
  if (which < 2){
    const float* src = pgs + which * 128 + t;
    for (int j = slice; j < nblk; j += 8) s += src[(size_t)j * 256];
    atomicAdd((which ? gsq : gsum) + t, s);
  } else {
    const float* src = dpart + t;
    for (int j = slice; j < DEN_BLK; j += 8) s += src[(size_t)j * 128];
    atomicAdd(denom + t, s);
  }
}

// ---------- finalize BN scale/shift + inverse denominators ----------
__global__ void finalizek(const float* __restrict__ sums, const float* __restrict__ sumsq,
                          const float* __restrict__ gamma, const float* __restrict__ beta,
                          const float* __restrict__ denom,
                          float* __restrict__ scalev, float* __restrict__ shiftv,
                          float* __restrict__ invden, int N){
  const int t = threadIdx.x;   // 128
  const float invN = 1.f / (float)N;
  const float mu = sums[t] * invN;
  const float var = sumsq[t] * invN - mu * mu;
  const float sc = gamma[t] * rsqrtf(var + 1e-5f);
  scalev[t] = sc;
  shiftv[t] = beta[t] - mu * sc;
  invden[t] = 1.f / denom[t];
}

// ---------- ctx partials with inline BN+ReLU (f32 x) ----------
__global__ __launch_bounds__(256) void ctx2k(const float* __restrict__ Xm,
                                             const float* __restrict__ wexp,
                                             const float* __restrict__ scalev,
                                             const float* __restrict__ shiftv,
                                             float* __restrict__ pbuf, int NPER){
  const int blk = blockIdx.x;
  const int b = blk >> 7, j = blk & 127;
  const int rows = (NPER + CTX_BPB - 1) / CTX_BPB;
  const int r0 = j * rows;
  const int r1 = min(r0 + rows, NPER);
  const int t = threadIdx.x, c = t & 127, rh = t >> 7;
  const float sc = scalev[c], sh = shiftv[c];
  float acc[KSLOT];
  #pragma unroll
  for (int k = 0; k < KSLOT; k++) acc[k] = 0.f;
  for (int r = r0 + rh; r < r1; r += 2){
    const size_t nn = (size_t)b * NPER + r;
    const float xv = fmaxf(fmaf(Xm[nn * C + c], sc, sh), 0.f);
    const float4* wr = reinterpret_cast<const float4*>(wexp + nn * KSLOT);
    #pragma unroll
    for (int kq = 0; kq < 8; kq++){
      const float4 w4 = wr[kq];
      acc[kq*4+0] = fmaf(w4.x, xv, acc[kq*4+0]);
      acc[kq*4+1] = fmaf(w4.y, xv, acc[kq*4+1]);
      acc[kq*4+2] = fmaf(w4.z, xv, acc[kq*4+2]);
      acc[kq*4+3] = fmaf(w4.w, xv, acc[kq*4+3]);
    }
  }
  __shared__ float red[2 * KSLOT * C];
  #pragma unroll
  for (int k = 0; k < KSLOT; k++) red[(rh * KSLOT + k) * C + c] = acc[k];
  __syncthreads();
  float* dst = pbuf + (size_t)blk * KSLOT * C;
  for (int i = t; i < KSLOT * C; i += 256) dst[i] = red[i] + red[KSLOT * C + i];
}

// ---------- kv: reduce ctx partials then project ----------
__global__ __launch_bounds__(256) void kvk(const float* __restrict__ pbuf,
                                           const float* __restrict__ invden,
                                           const unsigned short* __restrict__ WkvT,
                                           const float* __restrict__ inb,
                                           float* __restrict__ kh, float* __restrict__ vh){
  __shared__ float rowp[2][C];
  __shared__ float row[C];
  const int bk = blockIdx.x;              // b*32 + k
  const int b = bk >> 5, k = bk & 31;
  const int t = threadIdx.x, c = t & 127, jh = t >> 7;
  float s = 0.f;
  for (int j = jh; j < CTX_BPB; j += 2)
    s += pbuf[((size_t)(b * CTX_BPB + j) * KSLOT + k) * C + c];
  rowp[jh][c] = s;
  __syncthreads();
  if (t < C) row[t] = (rowp[0][t] + rowp[1][t]) * invden[b * KSLOT + k];
  __syncthreads();
  const int which = t >> 7;               // 0 -> K, 1 -> V
  const unsigned short* W = WkvT + (size_t)which * C * C;
  float acc = inb[(1 + which) * C + c];
  #pragma unroll 8
  for (int i = 0; i < C; i++) acc = fmaf(row[i], bf2f(W[i * C + c]), acc);
  (which ? vh : kh)[(size_t)bk * C + c] = acc;
}

// ---------- N x 128 @ (128x128)^T bf16 MFMA GEMM ----------
__global__ __launch_bounds__(256) void gemm128(
    const unsigned short* __restrict__ A, const unsigned short* __restrict__ W,
    const float* __restrict__ bias, float scale,
    float* __restrict__ outF, unsigned short* __restrict__ outB, int N)
{
  const int tid = threadIdx.x;
  const int wave = tid >> 6, lane = tid & 63;
  const int rbase = blockIdx.x * 64 + (wave >> 1) * 32;
  const int cbase = (wave & 1) * 64;
  const int lo = lane & 15, hi = lane >> 4;
  floatx4 acc[2][4];
  #pragma unroll
  for (int rt = 0; rt < 2; rt++)
    #pragma unroll
    for (int ct = 0; ct < 4; ct++) acc[rt][ct] = (floatx4){0.f,0.f,0.f,0.f};
  const int m0 = rbase + lo, m1 = rbase + 16 + lo;
  const int m0c = m0 < N ? m0 : N - 1;
  const int m1c = m1 < N ? m1 : N - 1;
  #pragma unroll
  for (int kc = 0; kc < 4; kc++){
    const int koff = kc * 32 + hi * 8;
    const short8 a0 = *reinterpret_cast<const short8*>(A + (size_t)m0c * C + koff);
    const short8 a1 = *reinterpret_cast<const short8*>(A + (size_t)m1c * C + koff);
    #pragma unroll
    for (int ct = 0; ct < 4; ct++){
      const int n = cbase + ct * 16 + lo;
      const short8 b = *reinterpret_cast<const short8*>(W + (size_t)n * C + koff);
      acc[0][ct] = __builtin_amdgcn_mfma_f32_16x16x32_bf16(a0, b, acc[0][ct], 0, 0, 0);
      acc[1][ct] = __builtin_amdgcn_mfma_f32_16x16x32_bf16(a1, b, acc[1][ct], 0, 0, 0);
    }
  }
  #pragma unroll
  for (int rt = 0; rt < 2; rt++){
    #pragma unroll
    for (int ct = 0; ct < 4; ct++){
      const int col = cbase + ct * 16 + lo;
      const float bv = bias ? bias[col] : 0.f;
      #pragma unroll
      for (int i = 0; i < 4; i++){
        const int row = rbase + rt * 16 + hi * 4 + i;
        if (row < N){
          const float v = (acc[rt][ct][i] + bv) * scale;
          if (outF) outF[(size_t)row * C + col] = v;
          if (outB) outB[(size_t)row * C + col] = f2bf(v);
        }
      }
    }
  }
}

// ---------- f32-A variant with inline BN+ReLU (for q projection) ----------
__global__ __launch_bounds__(256) void gemm128f(
    const float* __restrict__ A, const unsigned short* __restrict__ W,
    const float* __restrict__ bias, const float* __restrict__ bnsc,
    const float* __restrict__ bnsh, float scale,
    unsigned short* __restrict__ outB, int N)
{
  const int tid = threadIdx.x;
  const int wave = tid >> 6, lane = tid & 63;
  const int rbase = blockIdx.x * 64 + (wave >> 1) * 32;
  const int cbase = (wave & 1) * 64;
  const int lo = lane & 15, hi = lane >> 4;
  floatx4 acc[2][4];
  #pragma unroll
  for (int rt = 0; rt < 2; rt++)
    #pragma unroll
    for (int ct = 0; ct < 4; ct++) acc[rt][ct] = (floatx4){0.f,0.f,0.f,0.f};
  const int m0 = rbase + lo, m1 = rbase + 16 + lo;
  const int m0c = m0 < N ? m0 : N - 1;
  const int m1c = m1 < N ? m1 : N - 1;
  #pragma unroll
  for (int kc = 0; kc < 4; kc++){
    const int koff = kc * 32 + hi * 8;
    const float4 sc0 = *reinterpret_cast<const float4*>(bnsc + koff);
    const float4 sc1 = *reinterpret_cast<const float4*>(bnsc + koff + 4);
    const float4 sh0 = *reinterpret_cast<const float4*>(bnsh + koff);
    const float4 sh1 = *reinterpret_cast<const float4*>(bnsh + koff + 4);
    const float4 xa0 = *reinterpret_cast<const float4*>(A + (size_t)m0c * C + koff);
    const float4 xa1 = *reinterpret_cast<const float4*>(A + (size_t)m0c * C + koff + 4);
    const float4 xb0 = *reinterpret_cast<const float4*>(A + (size_t)m1c * C + koff);
    const float4 xb1 = *reinterpret_cast<const float4*>(A + (size_t)m1c * C + koff + 4);
    short8 a0, a1;
    const float* sc = &sc0.x; const float* sh = &sh0.x;
    const float* x0 = &xa0.x; const float* x1 = &xb0.x;
    #pragma unroll
    for (int j = 0; j < 4; j++){
      a0[j] = (short)f2bf(fmaxf(fmaf(x0[j], sc[j], sh[j]), 0.f));
      a1[j] = (short)f2bf(fmaxf(fmaf(x1[j], sc[j], sh[j]), 0.f));
    }
    const float* sc2 = &sc1.x; const float* sh2 = &sh1.x;
    const float* x02 = &xa1.x; const float* x12 = &xb1.x;
    #pragma unroll
    for (int j = 0; j < 4; j++){
      a0[4+j] = (short)f2bf(fmaxf(fmaf(x02[j], sc2[j], sh2[j]), 0.f));
      a1[4+j] = (short)f2bf(fmaxf(fmaf(x12[j], sc2[j], sh2[j]), 0.f));
    }
    #pragma unroll
    for (int ct = 0; ct < 4; ct++){
      const int n = cbase + ct * 16 + lo;
      const short8 b = *reinterpret_cast<const short8*>(W + (size_t)n * C + koff);
      acc[0][ct] = __builtin_amdgcn_mfma_f32_16x16x32_bf16(a0, b, acc[0][ct], 0, 0, 0);
      acc[1][ct] = __builtin_amdgcn_mfma_f32_16x16x32_bf16(a1, b, acc[1][ct], 0, 0, 0);
    }
  }
  #pragma unroll
  for (int rt = 0; rt < 2; rt++){
    #pragma unroll
    for (int ct = 0; ct < 4; ct++){
      const int col = cbase + ct * 16 + lo;
      const float bv = bias[col];
      #pragma unroll
      for (int i = 0; i < 4; i++){
        const int row = rbase + rt * 16 + hi * 4 + i;
        if (row < N) outB[(size_t)row * C + col] = f2bf((acc[rt][ct][i] + bv) * scale);
      }
    }
  }
}

// ---------- attention v3: thread owns (row, head); P stays in registers ----------
__global__ __launch_bounds__(256) void attn3k(const unsigned short* __restrict__ qb,
                                              const float* __restrict__ kh,
                                              const float* __restrict__ vh,
                                              unsigned short* __restrict__ ob, int NPER){
  __shared__ float khL[KSLOT * C];
  __shared__ float vhL[KSLOT * C];
  const int t = threadIdx.x;
  const int b = blockIdx.y;
  const int n0 = blockIdx.x * 32;
  {
    const float4* ks = reinterpret_cast<const float4*>(kh + (size_t)b * KSLOT * C);
    const float4* vs = reinterpret_cast<const float4*>(vh + (size_t)b * KSLOT * C);
    float4* kd = reinterpret_cast<float4*>(khL);
    float4* vd = reinterpret_cast<float4*>(vhL);
    #pragma unroll
    for (int i = 0; i < 4; i++){ kd[i * 256 + t] = ks[i * 256 + t]; vd[i * 256 + t] = vs[i * 256 + t]; }
  }
  __syncthreads();
  const int h = t >> 5, p = t & 31;
  const int n = n0 + p;
  const int nc = n < NPER ? n : NPER - 1;
  float qv[16];
  {
    const short8* qp = reinterpret_cast<const short8*>(qb + ((size_t)b * NPER + nc) * C + h * 16);
    const short8 qa = qp[0], qc = qp[1];
    #pragma unroll
    for (int i = 0; i < 8; i++){
      qv[i]     = bf2f((unsigned short)qa[i]);
      qv[8 + i] = bf2f((unsigned short)qc[i]);
    }
  }
  float sv[KSLOT];
  #pragma unroll
  for (int k = 0; k < KSLOT; k++){
    const float4* kp = reinterpret_cast<const float4*>(&khL[k * C + h * 16]);
    const float4 k0 = kp[0], k1 = kp[1], k2 = kp[2], k3 = kp[3];
    float s;
    s = qv[0] * k0.x;
    s = fmaf(qv[1], k0.y, s);  s = fmaf(qv[2],  k0.z, s);  s = fmaf(qv[3],  k0.w, s);
    s = fmaf(qv[4], k1.x, s);  s = fmaf(qv[5],  k1.y, s);  s = fmaf(qv[6],  k1.z, s);
    s = fmaf(qv[7], k1.w, s);  s = fmaf(qv[8],  k2.x, s);  s = fmaf(qv[9],  k2.y, s);
    s = fmaf(qv[10], k2.z, s); s = fmaf(qv[11], k2.w, s);  s = fmaf(qv[12], k3.x, s);
    s = fmaf(qv[13], k3.y, s); s = fmaf(qv[14], k3.z, s);  s = fmaf(qv[15], k3.w, s);
    sv[k] = s;
  }
  float m = sv[0];
  #pragma unroll
  for (int k = 1; k < KSLOT; k++) m = fmaxf(m, sv[k]);
  float sum = 0.f;
  #pragma unroll
  for (int k = 0; k < KSLOT; k++){ const float e = __expf(sv[k] - m); sv[k] = e; sum += e; }
  const float inv = 1.f / sum;
  float o[16];
  #pragma unroll
  for (int i = 0; i < 16; i++) o[i] = 0.f;
  #pragma unroll
  for (int k = 0; k < KSLOT; k++){
    const float w = sv[k];
    const float4* vp = reinterpret_cast<const float4*>(&vhL[k * C + h * 16]);
    const float4 v0 = vp[0], v1 = vp[1], v2 = vp[2], v3 = vp[3];
    o[0]  = fmaf(w, v0.x, o[0]);  o[1]  = fmaf(w, v0.y, o[1]);
    o[2]  = fmaf(w, v0.z, o[2]);  o[3]  = fmaf(w, v0.w, o[3]);
    o[4]  = fmaf(w, v1.x, o[4]);  o[5]  = fmaf(w, v1.y, o[5]);
    o[6]  = fmaf(w, v1.z, o[6]);  o[7]  = fmaf(w, v1.w, o[7]);
    o[8]  = fmaf(w, v2.x, o[8]);  o[9]  = fmaf(w, v2.y, o[9]);
    o[10] = fmaf(w, v2.z, o[10]); o[11] = fmaf(w, v2.w, o[11]);
    o[12] = fmaf(w, v3.x, o[12]); o[13] = fmaf(w, v3.y, o[13]);
    o[14] = fmaf(w, v3.z, o[14]); o[15] = fmaf(w, v3.w, o[15]);
  }
  if (n < NPER){
    short8 s0, s1;
    #pragma unroll
    for (int i = 0; i < 8; i++){
      s0[i] = (short)f2bf(o[i] * inv);
      s1[i] = (short)f2bf(o[8 + i] * inv);
    }
    unsigned short* op = ob + ((size_t)b * NPER + n) * C + h * 16;
    *reinterpret_cast<short8*>(op) = s0;
    *reinterpret_cast<short8*>(op + 8) = s1;
  }
}

extern "C" void kernel_launch(void* const* d_in, const int* in_sizes, int n_in,
                              void* d_out, int out_size, void* d_ws, size_t ws_size,
                              hipStream_t stream){
  const float* feats  = (const float*)d_in[0];
  const float* probs  = (const float*)d_in[1];
  const float* convw  = (const float*)d_in[2];
  const float* gamma  = (const float*)d_in[3];
  const float* beta   = (const float*)d_in[4];
  const float* inw    = (const float*)d_in[5];
  const float* inb    = (const float*)d_in[6];
  const float* outw   = (const float*)d_in[7];
  const float* outb   = (const float*)d_in[8];
  const float* bw     = (const float*)d_in[9];
  const int*   coords = (const int*)d_in[10];
  const int N = in_sizes[0] / C;
  const int NPER = N / NB;
  const int NBLK = (N + 63) / 64;

  char* ws = (char*)d_ws;
  size_t off = 0;
  auto alloc = [&](size_t bytes) -> char* {
    char* r = ws + off; off += (bytes + 255) & ~(size_t)255; return r;
  };
  int* grid_h            = (int*)alloc((size_t)NB * GRID3 * 4);          // 33.5 MB
  unsigned short* featsb = (unsigned short*)alloc((size_t)N * C * 2);    // 25.6 MB
  unsigned short* convwt = (unsigned short*)alloc((size_t)27 * C * C * 2);
  unsigned short* wq     = (unsigned short*)alloc((size_t)C * C * 2);
  unsigned short* wkvT   = (unsigned short*)alloc((size_t)2 * C * C * 2);
  unsigned short* w2b    = (unsigned short*)alloc((size_t)C * C * 2);
  float* b2              = (float*)alloc(512);
  float* xconv           = (float*)alloc((size_t)N * C * 4);             // 51.2 MB
  int2* pairs            = (int2*)alloc((size_t)27 * PCAP * 8);          // 1.7 MB
  float* spgs            = (float*)alloc((size_t)256 * 256 * 4);
  float* dpart           = (float*)alloc((size_t)DEN_BLK * 128 * 4);
  float* zero_base       = (float*)alloc((size_t)512 * 4);
  float* gsum   = zero_base;
  float* gsq    = zero_base + 128;
  float* denom  = zero_base + 256;
  int*   gcnt   = (int*)(zero_base + 384);    // 27 counters
  float* invden = (float*)alloc(512);
  float* scalev = (float*)alloc(512);
  float* shiftv = (float*)alloc(512);
  float* kh     = (float*)alloc((size_t)NB * KSLOT * C * 4);
  float* vh     = (float*)alloc((size_t)NB * KSLOT * C * 4);
  // aliases (lifetimes disjoint):
  float* wexp = (float*)grid_h;                  // grid dead after pairk
  float* pbuf = wexp + (size_t)N * KSLOT;        // +8.4 MB ctx partials
  unsigned short* qb   = (unsigned short*)(pbuf + (size_t)NB * CTX_BPB * KSLOT * C); // fits in 33.5MB region
  unsigned short* o_bf = featsb;                 // featsb dead after scatk

  const long total1 = (long)N * C;
  (void)hipMemsetAsync(grid_h, 0xFF, (size_t)NB * GRID3 * 4, stream);
  (void)hipMemsetAsync(zero_base, 0, (size_t)512 * 4, stream);
  prepk<<<2048, 256, 0, stream>>>(feats, convw, inw, featsb, convwt, wq, wkvT, total1);
  w2k<<<128, 128, 0, stream>>>(bw, outw, outb, w2b, b2);
  scatterk<<<(N + 255) / 256, 256, 0, stream>>>(coords, grid_h, N);
  pairk<<<(N + 255) / 256, 256, 0, stream>>>(coords, grid_h, pairs, gcnt, N);
  // grid_h dead; wexp/pbuf/qb alias it
  denomk<<<DEN_BLK, 256, 0, stream>>>(probs, coords, dpart, wexp, N);
  // center offset: dense GEMM writes xconv f32
  gemm128<<<NBLK, 256, 0, stream>>>(featsb, convwt + 13 * C * C, nullptr, 1.f, xconv, nullptr, N);
  // off-center offsets: compacted scatter-GEMM adds into xconv
  scatk<<<dim3(26, 32), 256, 0, stream>>>(featsb, convwt, pairs, gcnt, xconv, N);
  statsk<<<256, 256, 0, stream>>>(xconv, spgs, N);
  {
    dim3 rg(3, 8);
    reduk<<<rg, 128, 0, stream>>>(spgs, 256, dpart, gsum, gsq, denom);
  }
  finalizek<<<1, 128, 0, stream>>>(gsum, gsq, gamma, beta, denom, scalev, shiftv, invden, N);
  ctx2k<<<NB * CTX_BPB, 256, 0, stream>>>(xconv, wexp, scalev, shiftv, pbuf, NPER);
  kvk<<<NB * KSLOT, 256, 0, stream>>>(pbuf, invden, wkvT, inb, kh, vh);
  gemm128f<<<NBLK, 256, 0, stream>>>(xconv, wq, inb, scalev, shiftv, 0.25f, qb, N);
  dim3 agrid((NPER + 31) / 32, NB);
  attn3k<<<agrid, 256, 0, stream>>>(qb, kh, vh, o_bf, NPER);
  gemm128<<<NBLK, 256, 0, stream>>>(o_bf, w2b, b2, 1.f, (float*)d_out, nullptr, N);
}

// Round 8
// 473.938 us; speedup vs baseline: 2.2368x; 1.0274x over previous
//
#include <hip/hip_runtime.h>
#include <hip/hip_bf16.h>

typedef __attribute__((ext_vector_type(8))) short short8;
typedef __attribute__((ext_vector_type(4))) float floatx4;

#define NB 4
#define GRIDD 128
#define GRID3 (128*128*128)
#define C 128
#define KSLOT 32
#define CTX_BPB 256
#define DEN_BLK 1024
#define STAT_BLK 1024
#define PCAP 8192

static __device__ __forceinline__ unsigned short f2bf(float f){
  unsigned u = __builtin_bit_cast(unsigned, f);
  unsigned r = (u + 0x7FFFu + ((u >> 16) & 1u)) >> 16;
  return (unsigned short)r;
}
static __device__ __forceinline__ float bf2f(unsigned short h){
  unsigned u = ((unsigned)h) << 16;
  return __builtin_bit_cast(float, u);
}

// ---------- prep: bf16 conversions + transposes ----------
__global__ void prepk(const float* __restrict__ feats, const float* __restrict__ convw,
                      const float* __restrict__ inw,
                      unsigned short* __restrict__ Fb, unsigned short* __restrict__ Wt,
                      unsigned short* __restrict__ Wq, unsigned short* __restrict__ WkvT,
                      long total1)
{
  const long stride = (long)gridDim.x * blockDim.x;
  const long i0 = (long)blockIdx.x * blockDim.x + threadIdx.x;
  const long q4 = total1 >> 2;
  const float4* f4 = reinterpret_cast<const float4*>(feats);
  ushort4* fb4 = reinterpret_cast<ushort4*>(Fb);
  for (long i = i0; i < q4; i += stride){
    const float4 v = f4[i];
    ushort4 o; o.x = f2bf(v.x); o.y = f2bf(v.y); o.z = f2bf(v.z); o.w = f2bf(v.w);
    fb4[i] = o;
  }
  for (long i = i0; i < 27L*C*C; i += stride){
    long k = i >> 14; long r = (i >> 7) & 127; long c = i & 127;
    Wt[i] = f2bf(convw[(k << 14) + (c << 7) + r]);
  }
  for (long i = i0; i < C*C; i += stride) Wq[i] = f2bf(inw[i]);
  for (long i = i0; i < 2L*C*C; i += stride){
    long which = i >> 14, rem = i & 16383, ii = rem >> 7, cout = rem & 127;
    WkvT[i] = f2bf(inw[((1 + which) << 14) + (cout << 7) + ii]);
  }
}

// ---------- fold W2 = (bw[:, :128]+bw[:, 128:]) @ outw ; b2 = Wcf @ outb ----------
__global__ __launch_bounds__(128) void w2k(const float* __restrict__ bw,
                                           const float* __restrict__ outw,
                                           const float* __restrict__ outb,
                                           unsigned short* __restrict__ W2b,
                                           float* __restrict__ b2){
  const int o = blockIdx.x, i = threadIdx.x;
  __shared__ float wcf[128];
  __shared__ float red[128];
  const float w_i = bw[(size_t)o*256 + i] + bw[(size_t)o*256 + 128 + i];
  wcf[i] = w_i;
  red[i] = w_i * outb[i];
  __syncthreads();
  float acc = 0.f;
  #pragma unroll 8
  for (int j = 0; j < 128; j++) acc = fmaf(wcf[j], outw[j*128 + i], acc);
  W2b[o*128 + i] = f2bf(acc);
  for (int s = 64; s > 0; s >>= 1){
    if (i < s) red[i] += red[i + s];
    __syncthreads();
  }
  if (i == 0) b2[o] = red[0];
}

// ---------- scatter active sites into dense grid hash (grid NOT pre-cleared) ----------
__global__ void scatterk(const int* __restrict__ coords, int* __restrict__ gh, int N){
  int p = blockIdx.x * 256 + threadIdx.x;
  if (p < N){
    int4 cr = *reinterpret_cast<const int4*>(coords + (size_t)p * 4);
    gh[(((cr.x*GRIDD + cr.y)*GRIDD + cr.z)*GRIDD) + cr.w] = p;
  }
}

// ---------- pair lists per non-center offset; coords-validated (garbage-proof), ----------
// ---------- wave-aggregated counters (no per-lane atomic serialization)        ----------
__global__ __launch_bounds__(256) void pairk(const int* __restrict__ coords,
                                             const int* __restrict__ gh,
                                             int2* __restrict__ pairs,
                                             int* __restrict__ gcnt, int N){
  __shared__ int wcnt[4][27];
  __shared__ int woff[4][27];
  const int t = threadIdx.x, wave = t >> 6, lane = t & 63;
  const int p = blockIdx.x * 256 + t;
  const bool active = p < N;
  int4 cr = make_int4(0, 0, 0, 0);
  if (active) cr = *reinterpret_cast<const int4*>(coords + (size_t)p * 4);
  const int b = cr.x, x = cr.y, y = cr.z, z = cr.w;
  int jl[27];
  #pragma unroll
  for (int k = 0; k < 27; k++){
    jl[k] = -1;
    if (k == 13) continue;
    if (active){
      const int dx = k / 9 - 1, dy = (k / 3) % 3 - 1, dz = k % 3 - 1;
      const int nx = x + dx, ny = y + dy, nz = z + dz;
      if (((unsigned)nx < 128u) & ((unsigned)ny < 128u) & ((unsigned)nz < 128u)){
        const int gi = ((((b << 7) + nx) << 7) + ny) * GRIDD + nz;
        const int jj = gh[gi];
        if ((unsigned)jj < (unsigned)N){
          const int4 cj = *reinterpret_cast<const int4*>(coords + (size_t)jj * 4);
          if (cj.x == b && cj.y == nx && cj.z == ny && cj.w == nz) jl[k] = jj;
        }
      }
    }
  }
  #pragma unroll
  for (int k = 0; k < 27; k++){
    const unsigned long long m = __ballot(jl[k] >= 0);
    if (lane == 0) wcnt[wave][k] = (int)__popcll(m);
  }
  __syncthreads();
  if (t < 27){
    const int c0 = wcnt[0][t], c1 = wcnt[1][t], c2 = wcnt[2][t], c3 = wcnt[3][t];
    const int tot = c0 + c1 + c2 + c3;
    int gb = 0;
    if (t != 13 && tot > 0) gb = atomicAdd(&gcnt[t], tot);
    woff[0][t] = gb;
    woff[1][t] = gb + c0;
    woff[2][t] = gb + c0 + c1;
    woff[3][t] = gb + c0 + c1 + c2;
  }
  __syncthreads();
  const unsigned long long ltm = ((unsigned long long)1 << lane) - 1;
  #pragma unroll
  for (int k = 0; k < 27; k++){
    if (k == 13) continue;
    const unsigned long long m = __ballot(jl[k] >= 0);
    if (jl[k] >= 0){
      const int slot = woff[wave][k] + (int)__popcll(m & ltm);
      if (slot < PCAP) pairs[(size_t)k * PCAP + slot] = make_int2(p, jl[k]);
    }
  }
}

// ---------- off-center scatter-GEMM: Wt[k] in LDS, 16-pair chunks, atomic adds ----------
__global__ __launch_bounds__(256) void scatk(
    const unsigned short* __restrict__ F, const unsigned short* __restrict__ Wt,
    const int2* __restrict__ pairs, const int* __restrict__ gcnt,
    float* __restrict__ X, int N)
{
  __shared__ unsigned short wl[128 * 136];
  const int k = (blockIdx.x < 13) ? blockIdx.x : blockIdx.x + 1;
  const int t = threadIdx.x;
  const unsigned short* wg = Wt + (size_t)k * C * C;
  for (int idx = t; idx < 128 * 16; idx += 256){
    const int row = idx >> 4, seg = idx & 15;
    *reinterpret_cast<short8*>(&wl[row * 136 + seg * 8]) =
        *reinterpret_cast<const short8*>(wg + row * 128 + seg * 8);
  }
  __syncthreads();
  const int cnt = min(gcnt[k], PCAP);
  const int nch = (cnt + 15) >> 4;
  const int wave = t >> 6, lane = t & 63, lo = lane & 15, hi = lane >> 4;
  for (int c = blockIdx.y * 4 + wave; c < nch; c += 32 * 4){
    const int pidx = c * 16 + lo;
    const bool pv = pidx < cnt;
    const int2 pr = pv ? pairs[(size_t)k * PCAP + pidx] : make_int2(0, 0);
    const unsigned short* frow = F + (size_t)pr.y * C;
    short8 a[4];
    #pragma unroll
    for (int kc = 0; kc < 4; kc++){
      a[kc] = *reinterpret_cast<const short8*>(frow + kc * 32 + hi * 8);
      if (!pv) a[kc] = (short8){0,0,0,0,0,0,0,0};
    }
    floatx4 acc[8];
    #pragma unroll
    for (int i = 0; i < 8; i++) acc[i] = (floatx4){0.f,0.f,0.f,0.f};
    #pragma unroll
    for (int kc = 0; kc < 4; kc++){
      const int koff = kc * 32 + hi * 8;
      #pragma unroll
      for (int ct = 0; ct < 8; ct++){
        const short8 b = *reinterpret_cast<const short8*>(&wl[(ct*16 + lo) * 136 + koff]);
        acc[ct] = __builtin_amdgcn_mfma_f32_16x16x32_bf16(a[kc], b, acc[ct], 0, 0, 0);
      }
    }
    #pragma unroll
    for (int i2 = 0; i2 < 4; i2++){
      const int src = hi * 4 + i2;
      const int row = __shfl(pr.x, src);
      if (c * 16 + src < cnt){
        #pragma unroll
        for (int ct = 0; ct < 8; ct++)
          atomicAdd(&X[(size_t)row * C + ct * 16 + lo], acc[ct][i2]);
      }
    }
  }
}

// ---------- denom partials + wexp ----------
__global__ __launch_bounds__(256) void denomk(const float* __restrict__ probs,
                                              const int* __restrict__ coords,
                                              float* __restrict__ dpart,
                                              float* __restrict__ wexp, int N){
  const int t = threadIdx.x, k = t & 31, rh = t >> 5;
  float a0 = 0.f, a1 = 0.f, a2 = 0.f, a3 = 0.f;
  for (int r = blockIdx.x * 8 + rh; r < N; r += DEN_BLK * 8){
    const int b = coords[(size_t)r * 4];
    const float e = __expf(probs[(size_t)r * 32 + k]);
    wexp[(size_t)r * 32 + k] = e;
    a0 += (b == 0) ? e : 0.f;
    a1 += (b == 1) ? e : 0.f;
    a2 += (b == 2) ? e : 0.f;
    a3 += (b == 3) ? e : 0.f;
  }
  __shared__ float ls[8][128];
  ls[rh][0*32 + k] = a0; ls[rh][1*32 + k] = a1;
  ls[rh][2*32 + k] = a2; ls[rh][3*32 + k] = a3;
  __syncthreads();
  if (t < 128){
    float s = 0.f;
    #pragma unroll
    for (int j = 0; j < 8; j++) s += ls[j][t];
    dpart[(size_t)blockIdx.x * 128 + t] = s;
  }
}

// ---------- BN stat partials over f32 xconv: float4 lanes, 1024 blocks ----------
__global__ __launch_bounds__(256) void statsk(const float* __restrict__ X,
                                              float* __restrict__ spgs, int N){
  const int t = threadIdx.x, c4 = t & 31, rg = t >> 5;   // 32 float4/row, 8 rows/iter
  float s0=0.f,s1=0.f,s2=0.f,s3=0.f, q0=0.f,q1=0.f,q2=0.f,q3=0.f;
  for (int r = blockIdx.x * 8 + rg; r < N; r += STAT_BLK * 8){
    const float4 v = *reinterpret_cast<const float4*>(X + (size_t)r * C + c4 * 4);
    s0 += v.x; s1 += v.y; s2 += v.z; s3 += v.w;
    q0 = fmaf(v.x, v.x, q0); q1 = fmaf(v.y, v.y, q1);
    q2 = fmaf(v.z, v.z, q2); q3 = fmaf(v.w, v.w, q3);
  }
  __shared__ float ls[256][4], lq[256][4];
  ls[t][0]=s0; ls[t][1]=s1; ls[t][2]=s2; ls[t][3]=s3;
  lq[t][0]=q0; lq[t][1]=q1; lq[t][2]=q2; lq[t][3]=q3;
  __syncthreads();
  if (t < 32){
    float as[4]={0.f,0.f,0.f,0.f}, aq[4]={0.f,0.f,0.f,0.f};
    #pragma unroll
    for (int g = 0; g < 8; g++){
      #pragma unroll
      for (int j = 0; j < 4; j++){ as[j] += ls[g*32 + t][j]; aq[j] += lq[g*32 + t][j]; }
    }
    #pragma unroll
    for (int j = 0; j < 4; j++){
      spgs[(size_t)blockIdx.x * 256 + t*4 + j] = as[j];
      spgs[(size_t)blockIdx.x * 256 + 128 + t*4 + j] = aq[j];
    }
  }
}

// ---------- reduce partials: which=0 gsum, 1 gsq, 2 denom ----------
__global__ __launch_bounds__(128) void reduk(const float* __restrict__ pgs,
                                             const float* __restrict__ dpart,
                                             float* __restrict__ gsum,
                                             float* __restrict__ gsq,
                                             float* __restrict__ denom){
  const int which = blockIdx.x, slice = blockIdx.y, t = threadIdx.x;
  float s = 0.f;
  if (which < 2){
    const float* src = pgs + which * 128 + t;
    for (int j = slice; j < STAT_BLK; j += 8) s += src[(size_t)j * 256];
    atomicAdd((which ? gsq : gsum) + t, s);
  } else {
    const float* src = dpart + t;
    for (int j = slice; j < DEN_BLK; j += 8) s += src[(size_t)j * 128];
    atomicAdd(denom + t, s);
  }
}

// ---------- finalize BN scale/shift + inverse denominators ----------
__global__ void finalizek(const float* __restrict__ sums, const float* __restrict__ sumsq,
                          const float* __restrict__ gamma, const float* __restrict__ beta,
                          const float* __restrict__ denom,
                          float* __restrict__ scalev, float* __restrict__ shiftv,
                          float* __restrict__ invden, int N){
  const int t = threadIdx.x;   // 128
  const float invN = 1.f / (float)N;
  const float mu = sums[t] * invN;
  const float var = sumsq[t] * invN - mu * mu;
  const float sc = gamma[t] * rsqrtf(var + 1e-5f);
  scalev[t] = sc;
  shiftv[t] = beta[t] - mu * sc;
  invden[t] = 1.f / denom[t];
}

// ---------- ctx partials with inline BN+ReLU (f32 x), 1024 blocks ----------
__global__ __launch_bounds__(256) void ctx2k(const float* __restrict__ Xm,
                                             const float* __restrict__ wexp,
                                             const float* __restrict__ scalev,
                                             const float* __restrict__ shiftv,
                                             float* __restrict__ pbuf, int NPER){
  const int blk = blockIdx.x;
  const int b = blk >> 8, j = blk & 255;
  const int rows = (NPER + CTX_BPB - 1) / CTX_BPB;
  const int r0 = j * rows;
  const int r1 = min(r0 + rows, NPER);
  const int t = threadIdx.x, c = t & 127, rh = t >> 7;
  const float sc = scalev[c], sh = shiftv[c];
  float acc[KSLOT];
  #pragma unroll
  for (int k = 0; k < KSLOT; k++) acc[k] = 0.f;
  for (int r = r0 + rh; r < r1; r += 2){
    const size_t nn = (size_t)b * NPER + r;
    const float xv = fmaxf(fmaf(Xm[nn * C + c], sc, sh), 0.f);
    const float4* wr = reinterpret_cast<const float4*>(wexp + nn * KSLOT);
    #pragma unroll
    for (int kq = 0; kq < 8; kq++){
      const float4 w4 = wr[kq];
      acc[kq*4+0] = fmaf(w4.x, xv, acc[kq*4+0]);
      acc[kq*4+1] = fmaf(w4.y, xv, acc[kq*4+1]);
      acc[kq*4+2] = fmaf(w4.z, xv, acc[kq*4+2]);
      acc[kq*4+3] = fmaf(w4.w, xv, acc[kq*4+3]);
    }
  }
  __shared__ float red[2 * KSLOT * C];
  #pragma unroll
  for (int k = 0; k < KSLOT; k++) red[(rh * KSLOT + k) * C + c] = acc[k];
  __syncthreads();
  float* dst = pbuf + (size_t)blk * KSLOT * C;
  for (int i = t; i < KSLOT * C; i += 256) dst[i] = red[i] + red[KSLOT * C + i];
}

// ---------- kv: reduce ctx partials then project ----------
__global__ __launch_bounds__(256) void kvk(const float* __restrict__ pbuf,
                                           const float* __restrict__ invden,
                                           const unsigned short* __restrict__ WkvT,
                                           const float* __restrict__ inb,
                                           float* __restrict__ kh, float* __restrict__ vh){
  __shared__ float rowp[2][C];
  __shared__ float row[C];
  const int bk = blockIdx.x;              // b*32 + k
  const int b = bk >> 5, k = bk & 31;
  const int t = threadIdx.x, c = t & 127, jh = t >> 7;
  float s = 0.f;
  for (int j = jh; j < CTX_BPB; j += 2)
    s += pbuf[((size_t)(b * CTX_BPB + j) * KSLOT + k) * C + c];
  rowp[jh][c] = s;
  __syncthreads();
  if (t < C) row[t] = (rowp[0][t] + rowp[1][t]) * invden[b * KSLOT + k];
  __syncthreads();
  const int which = t >> 7;
  const unsigned short* W = WkvT + (size_t)which * C * C;
  float acc = inb[(1 + which) * C + c];
  #pragma unroll 8
  for (int i = 0; i < C; i++) acc = fmaf(row[i], bf2f(W[i * C + c]), acc);
  (which ? vh : kh)[(size_t)bk * C + c] = acc;
}

// ---------- N x 128 @ (128x128)^T bf16 MFMA GEMM ----------
__global__ __launch_bounds__(256) void gemm128(
    const unsigned short* __restrict__ A, const unsigned short* __restrict__ W,
    const float* __restrict__ bias, float scale,
    float* __restrict__ outF, unsigned short* __restrict__ outB, int N)
{
  const int tid = threadIdx.x;
  const int wave = tid >> 6, lane = tid & 63;
  const int rbase = blockIdx.x * 64 + (wave >> 1) * 32;
  const int cbase = (wave & 1) * 64;
  const int lo = lane & 15, hi = lane >> 4;
  floatx4 acc[2][4];
  #pragma unroll
  for (int rt = 0; rt < 2; rt++)
    #pragma unroll
    for (int ct = 0; ct < 4; ct++) acc[rt][ct] = (floatx4){0.f,0.f,0.f,0.f};
  const int m0 = rbase + lo, m1 = rbase + 16 + lo;
  const int m0c = m0 < N ? m0 : N - 1;
  const int m1c = m1 < N ? m1 : N - 1;
  #pragma unroll
  for (int kc = 0; kc < 4; kc++){
    const int koff = kc * 32 + hi * 8;
    const short8 a0 = *reinterpret_cast<const short8*>(A + (size_t)m0c * C + koff);
    const short8 a1 = *reinterpret_cast<const short8*>(A + (size_t)m1c * C + koff);
    #pragma unroll
    for (int ct = 0; ct < 4; ct++){
      const int n = cbase + ct * 16 + lo;
      const short8 b = *reinterpret_cast<const short8*>(W + (size_t)n * C + koff);
      acc[0][ct] = __builtin_amdgcn_mfma_f32_16x16x32_bf16(a0, b, acc[0][ct], 0, 0, 0);
      acc[1][ct] = __builtin_amdgcn_mfma_f32_16x16x32_bf16(a1, b, acc[1][ct], 0, 0, 0);
    }
  }
  #pragma unroll
  for (int rt = 0; rt < 2; rt++){
    #pragma unroll
    for (int ct = 0; ct < 4; ct++){
      const int col = cbase + ct * 16 + lo;
      const float bv = bias ? bias[col] : 0.f;
      #pragma unroll
      for (int i = 0; i < 4; i++){
        const int row = rbase + rt * 16 + hi * 4 + i;
        if (row < N){
          const float v = (acc[rt][ct][i] + bv) * scale;
          if (outF) outF[(size_t)row * C + col] = v;
          if (outB) outB[(size_t)row * C + col] = f2bf(v);
        }
      }
    }
  }
}

// ---------- f32-A variant with inline BN+ReLU (for q projection) ----------
__global__ __launch_bounds__(256) void gemm128f(
    const float* __restrict__ A, const unsigned short* __restrict__ W,
    const float* __restrict__ bias, const float* __restrict__ bnsc,
    const float* __restrict__ bnsh, float scale,
    unsigned short* __restrict__ outB, int N)
{
  const int tid = threadIdx.x;
  const int wave = tid >> 6, lane = tid & 63;
  const int rbase = blockIdx.x * 64 + (wave >> 1) * 32;
  const int cbase = (wave & 1) * 64;
  const int lo = lane & 15, hi = lane >> 4;
  floatx4 acc[2][4];
  #pragma unroll
  for (int rt = 0; rt < 2; rt++)
    #pragma unroll
    for (int ct = 0; ct < 4; ct++) acc[rt][ct] = (floatx4){0.f,0.f,0.f,0.f};
  const int m0 = rbase + lo, m1 = rbase + 16 + lo;
  const int m0c = m0 < N ? m0 : N - 1;
  const int m1c = m1 < N ? m1 : N - 1;
  #pragma unroll
  for (int kc = 0; kc < 4; kc++){
    const int koff = kc * 32 + hi * 8;
    short8 a0, a1;
    #pragma unroll
    for (int half = 0; half < 2; half++){
      const float4 sc = *reinterpret_cast<const float4*>(bnsc + koff + half * 4);
      const float4 sh = *reinterpret_cast<const float4*>(bnsh + koff + half * 4);
      const float4 x0 = *reinterpret_cast<const float4*>(A + (size_t)m0c * C + koff + half * 4);
      const float4 x1 = *reinterpret_cast<const float4*>(A + (size_t)m1c * C + koff + half * 4);
      const float* scp = &sc.x; const float* shp = &sh.x;
      const float* x0p = &x0.x; const float* x1p = &x1.x;
      #pragma unroll
      for (int j = 0; j < 4; j++){
        a0[half*4 + j] = (short)f2bf(fmaxf(fmaf(x0p[j], scp[j], shp[j]), 0.f));
        a1[half*4 + j] = (short)f2bf(fmaxf(fmaf(x1p[j], scp[j], shp[j]), 0.f));
      }
    }
    #pragma unroll
    for (int ct = 0; ct < 4; ct++){
      const int n = cbase + ct * 16 + lo;
      const short8 b = *reinterpret_cast<const short8*>(W + (size_t)n * C + koff);
      acc[0][ct] = __builtin_amdgcn_mfma_f32_16x16x32_bf16(a0, b, acc[0][ct], 0, 0, 0);
      acc[1][ct] = __builtin_amdgcn_mfma_f32_16x16x32_bf16(a1, b, acc[1][ct], 0, 0, 0);
    }
  }
  #pragma unroll
  for (int rt = 0; rt < 2; rt++){
    #pragma unroll
    for (int ct = 0; ct < 4; ct++){
      const int col = cbase + ct * 16 + lo;
      const float bv = bias[col];
      #pragma unroll
      for (int i = 0; i < 4; i++){
        const int row = rbase + rt * 16 + hi * 4 + i;
        if (row < N) outB[(size_t)row * C + col] = f2bf((acc[rt][ct][i] + bv) * scale);
      }
    }
  }
}

// ---------- attention v3: thread owns (row, head); P stays in registers ----------
__global__ __launch_bounds__(256) void attn3k(const unsigned short* __restrict__ qb,
                                              const float* __restrict__ kh,
                                              const float* __restrict__ vh,
                                              unsigned short* __restrict__ ob, int NPER){
  __shared__ float khL[KSLOT * C];
  __shared__ float vhL[KSLOT * C];
  const int t = threadIdx.x;
  const int b = blockIdx.y;
  const int n0 = blockIdx.x * 32;
  {
    const float4* ks = reinterpret_cast<const float4*>(kh + (size_t)b * KSLOT * C);
    const float4* vs = reinterpret_cast<const float4*>(vh + (size_t)b * KSLOT * C);
    float4* kd = reinterpret_cast<float4*>(khL);
    float4* vd = reinterpret_cast<float4*>(vhL);
    #pragma unroll
    for (int i = 0; i < 4; i++){ kd[i * 256 + t] = ks[i * 256 + t]; vd[i * 256 + t] = vs[i * 256 + t]; }
  }
  __syncthreads();
  const int h = t >> 5, p = t & 31;
  const int n = n0 + p;
  const int nc = n < NPER ? n : NPER - 1;
  float qv[16];
  {
    const short8* qp = reinterpret_cast<const short8*>(qb + ((size_t)b * NPER + nc) * C + h * 16);
    const short8 qa = qp[0], qc = qp[1];
    #pragma unroll
    for (int i = 0; i < 8; i++){
      qv[i]     = bf2f((unsigned short)qa[i]);
      qv[8 + i] = bf2f((unsigned short)qc[i]);
    }
  }
  float sv[KSLOT];
  #pragma unroll
  for (int k = 0; k < KSLOT; k++){
    const float4* kp = reinterpret_cast<const float4*>(&khL[k * C + h * 16]);
    const float4 k0 = kp[0], k1 = kp[1], k2 = kp[2], k3 = kp[3];
    float s;
    s = qv[0] * k0.x;
    s = fmaf(qv[1], k0.y, s);  s = fmaf(qv[2],  k0.z, s);  s = fmaf(qv[3],  k0.w, s);
    s = fmaf(qv[4], k1.x, s);  s = fmaf(qv[5],  k1.y, s);  s = fmaf(qv[6],  k1.z, s);
    s = fmaf(qv[7], k1.w, s);  s = fmaf(qv[8],  k2.x, s);  s = fmaf(qv[9],  k2.y, s);
    s = fmaf(qv[10], k2.z, s); s = fmaf(qv[11], k2.w, s);  s = fmaf(qv[12], k3.x, s);
    s = fmaf(qv[13], k3.y, s); s = fmaf(qv[14], k3.z, s);  s = fmaf(qv[15], k3.w, s);
    sv[k] = s;
  }
  float m = sv[0];
  #pragma unroll
  for (int k = 1; k < KSLOT; k++) m = fmaxf(m, sv[k]);
  float sum = 0.f;
  #pragma unroll
  for (int k = 0; k < KSLOT; k++){ const float e = __expf(sv[k] - m); sv[k] = e; sum += e; }
  const float inv = 1.f / sum;
  float o[16];
  #pragma unroll
  for (int i = 0; i < 16; i++) o[i] = 0.f;
  #pragma unroll
  for (int k = 0; k < KSLOT; k++){
    const float w = sv[k];
    const float4* vp = reinterpret_cast<const float4*>(&vhL[k * C + h * 16]);
    const float4 v0 = vp[0], v1 = vp[1], v2 = vp[2], v3 = vp[3];
    o[0]  = fmaf(w, v0.x, o[0]);  o[1]  = fmaf(w, v0.y, o[1]);
    o[2]  = fmaf(w, v0.z, o[2]);  o[3]  = fmaf(w, v0.w, o[3]);
    o[4]  = fmaf(w, v1.x, o[4]);  o[5]  = fmaf(w, v1.y, o[5]);
    o[6]  = fmaf(w, v1.z, o[6]);  o[7]  = fmaf(w, v1.w, o[7]);
    o[8]  = fmaf(w, v2.x, o[8]);  o[9]  = fmaf(w, v2.y, o[9]);
    o[10] = fmaf(w, v2.z, o[10]); o[11] = fmaf(w, v2.w, o[11]);
    o[12] = fmaf(w, v3.x, o[12]); o[13] = fmaf(w, v3.y, o[13]);
    o[14] = fmaf(w, v3.z, o[14]); o[15] = fmaf(w, v3.w, o[15]);
  }
  if (n < NPER){
    short8 s0, s1;
    #pragma unroll
    for (int i = 0; i < 8; i++){
      s0[i] = (short)f2bf(o[i] * inv);
      s1[i] = (short)f2bf(o[8 + i] * inv);
    }
    unsigned short* op = ob + ((size_t)b * NPER + n) * C + h * 16;
    *reinterpret_cast<short8*>(op) = s0;
    *reinterpret_cast<short8*>(op + 8) = s1;
  }
}

extern "C" void kernel_launch(void* const* d_in, const int* in_sizes, int n_in,
                              void* d_out, int out_size, void* d_ws, size_t ws_size,
                              hipStream_t stream){
  const float* feats  = (const float*)d_in[0];
  const float* probs  = (const float*)d_in[1];
  const float* convw  = (const float*)d_in[2];
  const float* gamma  = (const float*)d_in[3];
  const float* beta   = (const float*)d_in[4];
  const float* inw    = (const float*)d_in[5];
  const float* inb    = (const float*)d_in[6];
  const float* outw   = (const float*)d_in[7];
  const float* outb   = (const float*)d_in[8];
  const float* bw     = (const float*)d_in[9];
  const int*   coords = (const int*)d_in[10];
  const int N = in_sizes[0] / C;
  const int NPER = N / NB;
  const int NBLK = (N + 63) / 64;

  char* ws = (char*)d_ws;
  size_t off = 0;
  auto alloc = [&](size_t bytes) -> char* {
    char* r = ws + off; off += (bytes + 255) & ~(size_t)255; return r;
  };
  int* grid_h            = (int*)alloc((size_t)NB * GRID3 * 4);          // 33.5 MB (no memset)
  unsigned short* featsb = (unsigned short*)alloc((size_t)N * C * 2);    // 25.6 MB
  unsigned short* convwt = (unsigned short*)alloc((size_t)27 * C * C * 2);
  unsigned short* wq     = (unsigned short*)alloc((size_t)C * C * 2);
  unsigned short* wkvT   = (unsigned short*)alloc((size_t)2 * C * C * 2);
  unsigned short* w2b    = (unsigned short*)alloc((size_t)C * C * 2);
  float* b2              = (float*)alloc(512);
  float* xconv           = (float*)alloc((size_t)N * C * 4);             // 51.2 MB
  unsigned short* qb     = (unsigned short*)alloc((size_t)N * C * 2);    // 25.6 MB (dedicated!)
  int2* pairs            = (int2*)alloc((size_t)27 * PCAP * 8);          // 1.7 MB
  float* spgs            = (float*)alloc((size_t)STAT_BLK * 256 * 4);    // 1 MB
  float* dpart           = (float*)alloc((size_t)DEN_BLK * 128 * 4);     // 0.5 MB
  float* zero_base       = (float*)alloc((size_t)512 * 4);
  float* gsum   = zero_base;
  float* gsq    = zero_base + 128;
  float* denom  = zero_base + 256;
  int*   gcnt   = (int*)(zero_base + 384);
  float* invden = (float*)alloc(512);
  float* scalev = (float*)alloc(512);
  float* shiftv = (float*)alloc(512);
  float* kh     = (float*)alloc((size_t)NB * KSLOT * C * 4);
  float* vh     = (float*)alloc((size_t)NB * KSLOT * C * 4);
  // aliases (lifetimes disjoint):
  float* wexp = (float*)grid_h;                  // grid dead after pairk (12.8 MB)
  float* pbuf = wexp + (size_t)N * KSLOT;        // +16.8 MB ctx partials: 29.6 <= 33.5 OK
  unsigned short* o_bf = featsb;                 // featsb dead after scatk

  const long total1 = (long)N * C;
  (void)hipMemsetAsync(zero_base, 0, (size_t)512 * 4, stream);
  prepk<<<2048, 256, 0, stream>>>(feats, convw, inw, featsb, convwt, wq, wkvT, total1);
  w2k<<<128, 128, 0, stream>>>(bw, outw, outb, w2b, b2);
  scatterk<<<(N + 255) / 256, 256, 0, stream>>>(coords, grid_h, N);
  pairk<<<(N + 255) / 256, 256, 0, stream>>>(coords, grid_h, pairs, gcnt, N);
  // grid_h dead; wexp/pbuf alias it
  denomk<<<DEN_BLK, 256, 0, stream>>>(probs, coords, dpart, wexp, N);
  gemm128<<<NBLK, 256, 0, stream>>>(featsb, convwt + 13 * C * C, nullptr, 1.f, xconv, nullptr, N);
  scatk<<<dim3(26, 32), 256, 0, stream>>>(featsb, convwt, pairs, gcnt, xconv, N);
  statsk<<<STAT_BLK, 256, 0, stream>>>(xconv, spgs, N);
  {
    dim3 rg(3, 8);
    reduk<<<rg, 128, 0, stream>>>(spgs, dpart, gsum, gsq, denom);
  }
  finalizek<<<1, 128, 0, stream>>>(gsum, gsq, gamma, beta, denom, scalev, shiftv, invden, N);
  ctx2k<<<NB * CTX_BPB, 256, 0, stream>>>(xconv, wexp, scalev, shiftv, pbuf, NPER);
  kvk<<<NB * KSLOT, 256, 0, stream>>>(pbuf, invden, wkvT, inb, kh, vh);
  gemm128f<<<NBLK, 256, 0, stream>>>(xconv, wq, inb, scalev, shiftv, 0.25f, qb, N);
  dim3 agrid((NPER + 31) / 32, NB);
  attn3k<<<agrid, 256, 0, stream>>>(qb, kh, vh, o_bf, NPER);
  gemm128<<<NBLK, 256, 0, stream>>>(o_bf, w2b, b2, 1.f, (float*)d_out, nullptr, N);
}

// Round 9
// 456.229 us; speedup vs baseline: 2.3236x; 1.0388x over previous
//
#include <hip/hip_runtime.h>
#include <hip/hip_bf16.h>

typedef __attribute__((ext_vector_type(8))) short short8;
typedef __attribute__((ext_vector_type(4))) float floatx4;

#define NB 4
#define GRIDD 128
#define GRID3 (128*128*128)
#define C 128
#define KSLOT 32
#define CTX_BPB 256
#define DEN_BLK 1024
#define STAT_BLK 1024
#define PCAP 8192

static __device__ __forceinline__ unsigned short f2bf(float f){
  unsigned u = __builtin_bit_cast(unsigned, f);
  unsigned r = (u + 0x7FFFu + ((u >> 16) & 1u)) >> 16;
  return (unsigned short)r;
}
static __device__ __forceinline__ float bf2f(unsigned short h){
  unsigned u = ((unsigned)h) << 16;
  return __builtin_bit_cast(float, u);
}

// ---------- prep: bf16 conversions + transposes ----------
__global__ void prepk(const float* __restrict__ feats, const float* __restrict__ convw,
                      const float* __restrict__ inw,
                      unsigned short* __restrict__ Fb, unsigned short* __restrict__ Wt,
                      unsigned short* __restrict__ Wq, unsigned short* __restrict__ WkvT,
                      long total1)
{
  const long stride = (long)gridDim.x * blockDim.x;
  const long i0 = (long)blockIdx.x * blockDim.x + threadIdx.x;
  const long q4 = total1 >> 2;
  const float4* f4 = reinterpret_cast<const float4*>(feats);
  ushort4* fb4 = reinterpret_cast<ushort4*>(Fb);
  for (long i = i0; i < q4; i += stride){
    const float4 v = f4[i];
    ushort4 o; o.x = f2bf(v.x); o.y = f2bf(v.y); o.z = f2bf(v.z); o.w = f2bf(v.w);
    fb4[i] = o;
  }
  for (long i = i0; i < 27L*C*C; i += stride){
    long k = i >> 14; long r = (i >> 7) & 127; long c = i & 127;
    Wt[i] = f2bf(convw[(k << 14) + (c << 7) + r]);
  }
  for (long i = i0; i < C*C; i += stride) Wq[i] = f2bf(inw[i]);
  for (long i = i0; i < 2L*C*C; i += stride){
    long which = i >> 14, rem = i & 16383, ii = rem >> 7, cout = rem & 127;
    WkvT[i] = f2bf(inw[((1 + which) << 14) + (cout << 7) + ii]);
  }
}

// ---------- fold W2 = (bw[:, :128]+bw[:, 128:]) @ outw ; b2 = Wcf @ outb ----------
__global__ __launch_bounds__(128) void w2k(const float* __restrict__ bw,
                                           const float* __restrict__ outw,
                                           const float* __restrict__ outb,
                                           unsigned short* __restrict__ W2b,
                                           float* __restrict__ b2){
  const int o = blockIdx.x, i = threadIdx.x;
  __shared__ float wcf[128];
  __shared__ float red[128];
  const float w_i = bw[(size_t)o*256 + i] + bw[(size_t)o*256 + 128 + i];
  wcf[i] = w_i;
  red[i] = w_i * outb[i];
  __syncthreads();
  float acc = 0.f;
  #pragma unroll 8
  for (int j = 0; j < 128; j++) acc = fmaf(wcf[j], outw[j*128 + i], acc);
  W2b[o*128 + i] = f2bf(acc);
  for (int s = 64; s > 0; s >>= 1){
    if (i < s) red[i] += red[i + s];
    __syncthreads();
  }
  if (i == 0) b2[o] = red[0];
}

// ---------- scatter active sites into dense grid hash (grid NOT pre-cleared) ----------
__global__ void scatterk(const int* __restrict__ coords, int* __restrict__ gh, int N){
  int p = blockIdx.x * 256 + threadIdx.x;
  if (p < N){
    int4 cr = *reinterpret_cast<const int4*>(coords + (size_t)p * 4);
    gh[(((cr.x*GRIDD + cr.y)*GRIDD + cr.z)*GRIDD) + cr.w] = p;
  }
}

// ---------- pair lists; coords-validated (garbage-proof), wave-aggregated counts ----------
__global__ __launch_bounds__(256) void pairk(const int* __restrict__ coords,
                                             const int* __restrict__ gh,
                                             int2* __restrict__ pairs,
                                             int* __restrict__ gcnt, int N){
  __shared__ int wcnt[4][27];
  __shared__ int woff[4][27];
  const int t = threadIdx.x, wave = t >> 6, lane = t & 63;
  const int p = blockIdx.x * 256 + t;
  const bool active = p < N;
  int4 cr = make_int4(0, 0, 0, 0);
  if (active) cr = *reinterpret_cast<const int4*>(coords + (size_t)p * 4);
  const int b = cr.x, x = cr.y, y = cr.z, z = cr.w;
  int jl[27];
  #pragma unroll
  for (int k = 0; k < 27; k++){
    jl[k] = -1;
    if (k == 13) continue;
    if (active){
      const int dx = k / 9 - 1, dy = (k / 3) % 3 - 1, dz = k % 3 - 1;
      const int nx = x + dx, ny = y + dy, nz = z + dz;
      if (((unsigned)nx < 128u) & ((unsigned)ny < 128u) & ((unsigned)nz < 128u)){
        const int gi = ((((b << 7) + nx) << 7) + ny) * GRIDD + nz;
        const int jj = gh[gi];
        if ((unsigned)jj < (unsigned)N){
          const int4 cj = *reinterpret_cast<const int4*>(coords + (size_t)jj * 4);
          if (cj.x == b && cj.y == nx && cj.z == ny && cj.w == nz) jl[k] = jj;
        }
      }
    }
  }
  #pragma unroll
  for (int k = 0; k < 27; k++){
    const unsigned long long m = __ballot(jl[k] >= 0);
    if (lane == 0) wcnt[wave][k] = (int)__popcll(m);
  }
  __syncthreads();
  if (t < 27){
    const int c0 = wcnt[0][t], c1 = wcnt[1][t], c2 = wcnt[2][t], c3 = wcnt[3][t];
    const int tot = c0 + c1 + c2 + c3;
    int gb = 0;
    if (t != 13 && tot > 0) gb = atomicAdd(&gcnt[t], tot);
    woff[0][t] = gb;
    woff[1][t] = gb + c0;
    woff[2][t] = gb + c0 + c1;
    woff[3][t] = gb + c0 + c1 + c2;
  }
  __syncthreads();
  const unsigned long long ltm = ((unsigned long long)1 << lane) - 1;
  #pragma unroll
  for (int k = 0; k < 27; k++){
    if (k == 13) continue;
    const unsigned long long m = __ballot(jl[k] >= 0);
    if (jl[k] >= 0){
      const int slot = woff[wave][k] + (int)__popcll(m & ltm);
      if (slot < PCAP) pairs[(size_t)k * PCAP + slot] = make_int2(p, jl[k]);
    }
  }
}

// ---------- off-center scatter-GEMM: Wt[k] in LDS, 16-pair chunks, atomic adds ----------
__global__ __launch_bounds__(256) void scatk(
    const unsigned short* __restrict__ F, const unsigned short* __restrict__ Wt,
    const int2* __restrict__ pairs, const int* __restrict__ gcnt,
    float* __restrict__ X, int N)
{
  __shared__ unsigned short wl[128 * 136];
  const int k = (blockIdx.x < 13) ? blockIdx.x : blockIdx.x + 1;
  const int t = threadIdx.x;
  const unsigned short* wg = Wt + (size_t)k * C * C;
  for (int idx = t; idx < 128 * 16; idx += 256){
    const int row = idx >> 4, seg = idx & 15;
    *reinterpret_cast<short8*>(&wl[row * 136 + seg * 8]) =
        *reinterpret_cast<const short8*>(wg + row * 128 + seg * 8);
  }
  __syncthreads();
  const int cnt = min(gcnt[k], PCAP);
  const int nch = (cnt + 15) >> 4;
  const int wave = t >> 6, lane = t & 63, lo = lane & 15, hi = lane >> 4;
  for (int c = blockIdx.y * 4 + wave; c < nch; c += 32 * 4){
    const int pidx = c * 16 + lo;
    const bool pv = pidx < cnt;
    const int2 pr = pv ? pairs[(size_t)k * PCAP + pidx] : make_int2(0, 0);
    const unsigned short* frow = F + (size_t)pr.y * C;
    short8 a[4];
    #pragma unroll
    for (int kc = 0; kc < 4; kc++){
      a[kc] = *reinterpret_cast<const short8*>(frow + kc * 32 + hi * 8);
      if (!pv) a[kc] = (short8){0,0,0,0,0,0,0,0};
    }
    floatx4 acc[8];
    #pragma unroll
    for (int i = 0; i < 8; i++) acc[i] = (floatx4){0.f,0.f,0.f,0.f};
    #pragma unroll
    for (int kc = 0; kc < 4; kc++){
      const int koff = kc * 32 + hi * 8;
      #pragma unroll
      for (int ct = 0; ct < 8; ct++){
        const short8 b = *reinterpret_cast<const short8*>(&wl[(ct*16 + lo) * 136 + koff]);
        acc[ct] = __builtin_amdgcn_mfma_f32_16x16x32_bf16(a[kc], b, acc[ct], 0, 0, 0);
      }
    }
    #pragma unroll
    for (int i2 = 0; i2 < 4; i2++){
      const int src = hi * 4 + i2;
      const int row = __shfl(pr.x, src);
      if (c * 16 + src < cnt){
        #pragma unroll
        for (int ct = 0; ct < 8; ct++)
          atomicAdd(&X[(size_t)row * C + ct * 16 + lo], acc[ct][i2]);
      }
    }
  }
}

// ---------- denom partials (no wexp materialization) ----------
__global__ __launch_bounds__(256) void denomk(const float* __restrict__ probs,
                                              const int* __restrict__ coords,
                                              float* __restrict__ dpart, int N){
  const int t = threadIdx.x, k = t & 31, rh = t >> 5;
  float a0 = 0.f, a1 = 0.f, a2 = 0.f, a3 = 0.f;
  for (int r = blockIdx.x * 8 + rh; r < N; r += DEN_BLK * 8){
    const int b = coords[(size_t)r * 4];
    const float e = __expf(probs[(size_t)r * 32 + k]);
    a0 += (b == 0) ? e : 0.f;
    a1 += (b == 1) ? e : 0.f;
    a2 += (b == 2) ? e : 0.f;
    a3 += (b == 3) ? e : 0.f;
  }
  __shared__ float ls[8][128];
  ls[rh][0*32 + k] = a0; ls[rh][1*32 + k] = a1;
  ls[rh][2*32 + k] = a2; ls[rh][3*32 + k] = a3;
  __syncthreads();
  if (t < 128){
    float s = 0.f;
    #pragma unroll
    for (int j = 0; j < 8; j++) s += ls[j][t];
    dpart[(size_t)blockIdx.x * 128 + t] = s;
  }
}

// ---------- BN stat partials over f32 xconv: float4 lanes ----------
__global__ __launch_bounds__(256) void statsk(const float* __restrict__ X,
                                              float* __restrict__ spgs, int N){
  const int t = threadIdx.x, c4 = t & 31, rg = t >> 5;
  float s0=0.f,s1=0.f,s2=0.f,s3=0.f, q0=0.f,q1=0.f,q2=0.f,q3=0.f;
  for (int r = blockIdx.x * 8 + rg; r < N; r += STAT_BLK * 8){
    const float4 v = *reinterpret_cast<const float4*>(X + (size_t)r * C + c4 * 4);
    s0 += v.x; s1 += v.y; s2 += v.z; s3 += v.w;
    q0 = fmaf(v.x, v.x, q0); q1 = fmaf(v.y, v.y, q1);
    q2 = fmaf(v.z, v.z, q2); q3 = fmaf(v.w, v.w, q3);
  }
  __shared__ float ls[256][4], lq[256][4];
  ls[t][0]=s0; ls[t][1]=s1; ls[t][2]=s2; ls[t][3]=s3;
  lq[t][0]=q0; lq[t][1]=q1; lq[t][2]=q2; lq[t][3]=q3;
  __syncthreads();
  if (t < 32){
    float as[4]={0.f,0.f,0.f,0.f}, aq[4]={0.f,0.f,0.f,0.f};
    #pragma unroll
    for (int g = 0; g < 8; g++){
      #pragma unroll
      for (int j = 0; j < 4; j++){ as[j] += ls[g*32 + t][j]; aq[j] += lq[g*32 + t][j]; }
    }
    #pragma unroll
    for (int j = 0; j < 4; j++){
      spgs[(size_t)blockIdx.x * 256 + t*4 + j] = as[j];
      spgs[(size_t)blockIdx.x * 256 + 128 + t*4 + j] = aq[j];
    }
  }
}

// ---------- reduce partials: which=0 gsum, 1 gsq, 2 denom ----------
__global__ __launch_bounds__(128) void reduk(const float* __restrict__ pgs,
                                             const float* __restrict__ dpart,
                                             float* __restrict__ gsum,
                                             float* __restrict__ gsq,
                                             float* __restrict__ denom){
  const int which = blockIdx.x, slice = blockIdx.y, t = threadIdx.x;
  float s = 0.f;
  if (which < 2){
    const float* src = pgs + which * 128 + t;
    for (int j = slice; j < STAT_BLK; j += 8) s += src[(size_t)j * 256];
    atomicAdd((which ? gsq : gsum) + t, s);
  } else {
    const float* src = dpart + t;
    for (int j = slice; j < DEN_BLK; j += 8) s += src[(size_t)j * 128];
    atomicAdd(denom + t, s);
  }
}

// ---------- finalize BN scale/shift + inverse denominators ----------
__global__ void finalizek(const float* __restrict__ sums, const float* __restrict__ sumsq,
                          const float* __restrict__ gamma, const float* __restrict__ beta,
                          const float* __restrict__ denom,
                          float* __restrict__ scalev, float* __restrict__ shiftv,
                          float* __restrict__ invden, int N){
  const int t = threadIdx.x;   // 128
  const float invN = 1.f / (float)N;
  const float mu = sums[t] * invN;
  const float var = sumsq[t] * invN - mu * mu;
  const float sc = gamma[t] * rsqrtf(var + 1e-5f);
  scalev[t] = sc;
  shiftv[t] = beta[t] - mu * sc;
  invden[t] = 1.f / denom[t];
}

// ---------- ctx partials v2: LDS-staged tiles, exp recomputed, inline BN+ReLU ----------
__global__ __launch_bounds__(256) void ctx2k(const float* __restrict__ Xm,
                                             const float* __restrict__ probs,
                                             const float* __restrict__ scalev,
                                             const float* __restrict__ shiftv,
                                             float* __restrict__ pbuf, int NPER){
  __shared__ float xL[32 * 128];       // 16 KB raw x tile
  __shared__ float pe[32 * 32];        // 4 KB exp(probs) tile
  __shared__ float red[2 * KSLOT * C]; // 32 KB reduction
  const int blk = blockIdx.x;
  const int b = blk >> 8, j = blk & 255;
  const int rows = (NPER + CTX_BPB - 1) / CTX_BPB;
  const int r0 = j * rows;
  const int r1 = min(r0 + rows, NPER);
  const int t = threadIdx.x, c = t & 127, rh = t >> 7;
  const float sc = scalev[c], sh = shiftv[c];
  float acc[KSLOT];
  #pragma unroll
  for (int k = 0; k < KSLOT; k++) acc[k] = 0.f;

  for (int base = r0; base < r1; base += 32){
    __syncthreads();
    // stage x tile: 1024 float4, 4 per thread, fully independent coalesced
    #pragma unroll
    for (int i = 0; i < 4; i++){
      const int idx = i * 256 + t;
      const int r = idx >> 5, c4 = idx & 31;
      const int rr = base + r;
      float4 v = make_float4(0.f, 0.f, 0.f, 0.f);
      if (rr < r1) v = *reinterpret_cast<const float4*>(Xm + ((size_t)b * NPER + rr) * C + c4 * 4);
      *reinterpret_cast<float4*>(&xL[r * 128 + c4 * 4]) = v;
    }
    // stage exp(probs) tile: 256 float4, 1 per thread; invalid rows -> 0
    {
      const int r = t >> 3, k4 = t & 7;
      const int rr = base + r;
      float4 v = make_float4(0.f, 0.f, 0.f, 0.f);
      if (rr < r1){
        const float4 pv = *reinterpret_cast<const float4*>(probs + ((size_t)b * NPER + rr) * 32 + k4 * 4);
        v.x = __expf(pv.x); v.y = __expf(pv.y); v.z = __expf(pv.z); v.w = __expf(pv.w);
      }
      *reinterpret_cast<float4*>(&pe[r * 32 + k4 * 4]) = v;
    }
    __syncthreads();
    const int rend = min(32, r1 - base);
    for (int r = rh; r < rend; r += 2){
      const float xv = fmaxf(fmaf(xL[r * 128 + c], sc, sh), 0.f);
      const float4* wr = reinterpret_cast<const float4*>(&pe[r * 32]);
      #pragma unroll
      for (int kq = 0; kq < 8; kq++){
        const float4 w4 = wr[kq];   // wave-broadcast (same addr all lanes)
        acc[kq*4+0] = fmaf(w4.x, xv, acc[kq*4+0]);
        acc[kq*4+1] = fmaf(w4.y, xv, acc[kq*4+1]);
        acc[kq*4+2] = fmaf(w4.z, xv, acc[kq*4+2]);
        acc[kq*4+3] = fmaf(w4.w, xv, acc[kq*4+3]);
      }
    }
  }
  __syncthreads();
  #pragma unroll
  for (int k = 0; k < KSLOT; k++) red[(rh * KSLOT + k) * C + c] = acc[k];
  __syncthreads();
  float* dst = pbuf + (size_t)blk * KSLOT * C;
  for (int i = t; i < KSLOT * C; i += 256) dst[i] = red[i] + red[KSLOT * C + i];
}

// ---------- kv: reduce ctx partials then project ----------
__global__ __launch_bounds__(256) void kvk(const float* __restrict__ pbuf,
                                           const float* __restrict__ invden,
                                           const unsigned short* __restrict__ WkvT,
                                           const float* __restrict__ inb,
                                           float* __restrict__ kh, float* __restrict__ vh){
  __shared__ float rowp[2][C];
  __shared__ float row[C];
  const int bk = blockIdx.x;              // b*32 + k
  const int b = bk >> 5, k = bk & 31;
  const int t = threadIdx.x, c = t & 127, jh = t >> 7;
  float s = 0.f;
  for (int j = jh; j < CTX_BPB; j += 2)
    s += pbuf[((size_t)(b * CTX_BPB + j) * KSLOT + k) * C + c];
  rowp[jh][c] = s;
  __syncthreads();
  if (t < C) row[t] = (rowp[0][t] + rowp[1][t]) * invden[b * KSLOT + k];
  __syncthreads();
  const int which = t >> 7;
  const unsigned short* W = WkvT + (size_t)which * C * C;
  float acc = inb[(1 + which) * C + c];
  #pragma unroll 8
  for (int i = 0; i < C; i++) acc = fmaf(row[i], bf2f(W[i * C + c]), acc);
  (which ? vh : kh)[(size_t)bk * C + c] = acc;
}

// ---------- N x 128 @ (128x128)^T bf16 MFMA GEMM ----------
__global__ __launch_bounds__(256) void gemm128(
    const unsigned short* __restrict__ A, const unsigned short* __restrict__ W,
    const float* __restrict__ bias, float scale,
    float* __restrict__ outF, unsigned short* __restrict__ outB, int N)
{
  const int tid = threadIdx.x;
  const int wave = tid >> 6, lane = tid & 63;
  const int rbase = blockIdx.x * 64 + (wave >> 1) * 32;
  const int cbase = (wave & 1) * 64;
  const int lo = lane & 15, hi = lane >> 4;
  floatx4 acc[2][4];
  #pragma unroll
  for (int rt = 0; rt < 2; rt++)
    #pragma unroll
    for (int ct = 0; ct < 4; ct++) acc[rt][ct] = (floatx4){0.f,0.f,0.f,0.f};
  const int m0 = rbase + lo, m1 = rbase + 16 + lo;
  const int m0c = m0 < N ? m0 : N - 1;
  const int m1c = m1 < N ? m1 : N - 1;
  #pragma unroll
  for (int kc = 0; kc < 4; kc++){
    const int koff = kc * 32 + hi * 8;
    const short8 a0 = *reinterpret_cast<const short8*>(A + (size_t)m0c * C + koff);
    const short8 a1 = *reinterpret_cast<const short8*>(A + (size_t)m1c * C + koff);
    #pragma unroll
    for (int ct = 0; ct < 4; ct++){
      const int n = cbase + ct * 16 + lo;
      const short8 b = *reinterpret_cast<const short8*>(W + (size_t)n * C + koff);
      acc[0][ct] = __builtin_amdgcn_mfma_f32_16x16x32_bf16(a0, b, acc[0][ct], 0, 0, 0);
      acc[1][ct] = __builtin_amdgcn_mfma_f32_16x16x32_bf16(a1, b, acc[1][ct], 0, 0, 0);
    }
  }
  #pragma unroll
  for (int rt = 0; rt < 2; rt++){
    #pragma unroll
    for (int ct = 0; ct < 4; ct++){
      const int col = cbase + ct * 16 + lo;
      const float bv = bias ? bias[col] : 0.f;
      #pragma unroll
      for (int i = 0; i < 4; i++){
        const int row = rbase + rt * 16 + hi * 4 + i;
        if (row < N){
          const float v = (acc[rt][ct][i] + bv) * scale;
          if (outF) outF[(size_t)row * C + col] = v;
          if (outB) outB[(size_t)row * C + col] = f2bf(v);
        }
      }
    }
  }
}

// ---------- f32-A variant with inline BN+ReLU (for q projection) ----------
__global__ __launch_bounds__(256) void gemm128f(
    const float* __restrict__ A, const unsigned short* __restrict__ W,
    const float* __restrict__ bias, const float* __restrict__ bnsc,
    const float* __restrict__ bnsh, float scale,
    unsigned short* __restrict__ outB, int N)
{
  const int tid = threadIdx.x;
  const int wave = tid >> 6, lane = tid & 63;
  const int rbase = blockIdx.x * 64 + (wave >> 1) * 32;
  const int cbase = (wave & 1) * 64;
  const int lo = lane & 15, hi = lane >> 4;
  floatx4 acc[2][4];
  #pragma unroll
  for (int rt = 0; rt < 2; rt++)
    #pragma unroll
    for (int ct = 0; ct < 4; ct++) acc[rt][ct] = (floatx4){0.f,0.f,0.f,0.f};
  const int m0 = rbase + lo, m1 = rbase + 16 + lo;
  const int m0c = m0 < N ? m0 : N - 1;
  const int m1c = m1 < N ? m1 : N - 1;
  #pragma unroll
  for (int kc = 0; kc < 4; kc++){
    const int koff = kc * 32 + hi * 8;
    short8 a0, a1;
    #pragma unroll
    for (int half = 0; half < 2; half++){
      const float4 sc = *reinterpret_cast<const float4*>(bnsc + koff + half * 4);
      const float4 sh = *reinterpret_cast<const float4*>(bnsh + koff + half * 4);
      const float4 x0 = *reinterpret_cast<const float4*>(A + (size_t)m0c * C + koff + half * 4);
      const float4 x1 = *reinterpret_cast<const float4*>(A + (size_t)m1c * C + koff + half * 4);
      const float* scp = &sc.x; const float* shp = &sh.x;
      const float* x0p = &x0.x; const float* x1p = &x1.x;
      #pragma unroll
      for (int j = 0; j < 4; j++){
        a0[half*4 + j] = (short)f2bf(fmaxf(fmaf(x0p[j], scp[j], shp[j]), 0.f));
        a1[half*4 + j] = (short)f2bf(fmaxf(fmaf(x1p[j], scp[j], shp[j]), 0.f));
      }
    }
    #pragma unroll
    for (int ct = 0; ct < 4; ct++){
      const int n = cbase + ct * 16 + lo;
      const short8 b = *reinterpret_cast<const short8*>(W + (size_t)n * C + koff);
      acc[0][ct] = __builtin_amdgcn_mfma_f32_16x16x32_bf16(a0, b, acc[0][ct], 0, 0, 0);
      acc[1][ct] = __builtin_amdgcn_mfma_f32_16x16x32_bf16(a1, b, acc[1][ct], 0, 0, 0);
    }
  }
  #pragma unroll
  for (int rt = 0; rt < 2; rt++){
    #pragma unroll
    for (int ct = 0; ct < 4; ct++){
      const int col = cbase + ct * 16 + lo;
      const float bv = bias[col];
      #pragma unroll
      for (int i = 0; i < 4; i++){
        const int row = rbase + rt * 16 + hi * 4 + i;
        if (row < N) outB[(size_t)row * C + col] = f2bf((acc[rt][ct][i] + bv) * scale);
      }
    }
  }
}

// ---------- attention v3b: 64 rows/block, thread owns (row, head) ----------
__global__ __launch_bounds__(256) void attn3k(const unsigned short* __restrict__ qb,
                                              const float* __restrict__ kh,
                                              const float* __restrict__ vh,
                                              unsigned short* __restrict__ ob, int NPER){
  __shared__ float khL[KSLOT * C];
  __shared__ float vhL[KSLOT * C];
  const int t = threadIdx.x;
  const int b = blockIdx.y;
  const int n0 = blockIdx.x * 64;
  {
    const float4* ks = reinterpret_cast<const float4*>(kh + (size_t)b * KSLOT * C);
    const float4* vs = reinterpret_cast<const float4*>(vh + (size_t)b * KSLOT * C);
    float4* kd = reinterpret_cast<float4*>(khL);
    float4* vd = reinterpret_cast<float4*>(vhL);
    #pragma unroll
    for (int i = 0; i < 4; i++){ kd[i * 256 + t] = ks[i * 256 + t]; vd[i * 256 + t] = vs[i * 256 + t]; }
  }
  __syncthreads();
  const int h = t >> 5, p = t & 31;
  for (int g = 0; g < 2; g++){
    const int n = n0 + g * 32 + p;
    const int nc = n < NPER ? n : NPER - 1;
    float qv[16];
    {
      const short8* qp = reinterpret_cast<const short8*>(qb + ((size_t)b * NPER + nc) * C + h * 16);
      const short8 qa = qp[0], qc = qp[1];
      #pragma unroll
      for (int i = 0; i < 8; i++){
        qv[i]     = bf2f((unsigned short)qa[i]);
        qv[8 + i] = bf2f((unsigned short)qc[i]);
      }
    }
    float sv[KSLOT];
    #pragma unroll
    for (int k = 0; k < KSLOT; k++){
      const float4* kp = reinterpret_cast<const float4*>(&khL[k * C + h * 16]);
      const float4 k0 = kp[0], k1 = kp[1], k2 = kp[2], k3 = kp[3];
      float s;
      s = qv[0] * k0.x;
      s = fmaf(qv[1], k0.y, s);  s = fmaf(qv[2],  k0.z, s);  s = fmaf(qv[3],  k0.w, s);
      s = fmaf(qv[4], k1.x, s);  s = fmaf(qv[5],  k1.y, s);  s = fmaf(qv[6],  k1.z, s);
      s = fmaf(qv[7], k1.w, s);  s = fmaf(qv[8],  k2.x, s);  s = fmaf(qv[9],  k2.y, s);
      s = fmaf(qv[10], k2.z, s); s = fmaf(qv[11], k2.w, s);  s = fmaf(qv[12], k3.x, s);
      s = fmaf(qv[13], k3.y, s); s = fmaf(qv[14], k3.z, s);  s = fmaf(qv[15], k3.w, s);
      sv[k] = s;
    }
    float m = sv[0];
    #pragma unroll
    for (int k = 1; k < KSLOT; k++) m = fmaxf(m, sv[k]);
    float sum = 0.f;
    #pragma unroll
    for (int k = 0; k < KSLOT; k++){ const float e = __expf(sv[k] - m); sv[k] = e; sum += e; }
    const float inv = 1.f / sum;
    float o[16];
    #pragma unroll
    for (int i = 0; i < 16; i++) o[i] = 0.f;
    #pragma unroll
    for (int k = 0; k < KSLOT; k++){
      const float w = sv[k];
      const float4* vp = reinterpret_cast<const float4*>(&vhL[k * C + h * 16]);
      const float4 v0 = vp[0], v1 = vp[1], v2 = vp[2], v3 = vp[3];
      o[0]  = fmaf(w, v0.x, o[0]);  o[1]  = fmaf(w, v0.y, o[1]);
      o[2]  = fmaf(w, v0.z, o[2]);  o[3]  = fmaf(w, v0.w, o[3]);
      o[4]  = fmaf(w, v1.x, o[4]);  o[5]  = fmaf(w, v1.y, o[5]);
      o[6]  = fmaf(w, v1.z, o[6]);  o[7]  = fmaf(w, v1.w, o[7]);
      o[8]  = fmaf(w, v2.x, o[8]);  o[9]  = fmaf(w, v2.y, o[9]);
      o[10] = fmaf(w, v2.z, o[10]); o[11] = fmaf(w, v2.w, o[11]);
      o[12] = fmaf(w, v3.x, o[12]); o[13] = fmaf(w, v3.y, o[13]);
      o[14] = fmaf(w, v3.z, o[14]); o[15] = fmaf(w, v3.w, o[15]);
    }
    if (n < NPER){
      short8 s0, s1;
      #pragma unroll
      for (int i = 0; i < 8; i++){
        s0[i] = (short)f2bf(o[i] * inv);
        s1[i] = (short)f2bf(o[8 + i] * inv);
      }
      unsigned short* op = ob + ((size_t)b * NPER + n) * C + h * 16;
      *reinterpret_cast<short8*>(op) = s0;
      *reinterpret_cast<short8*>(op + 8) = s1;
    }
  }
}

extern "C" void kernel_launch(void* const* d_in, const int* in_sizes, int n_in,
                              void* d_out, int out_size, void* d_ws, size_t ws_size,
                              hipStream_t stream){
  const float* feats  = (const float*)d_in[0];
  const float* probs  = (const float*)d_in[1];
  const float* convw  = (const float*)d_in[2];
  const float* gamma  = (const float*)d_in[3];
  const float* beta   = (const float*)d_in[4];
  const float* inw    = (const float*)d_in[5];
  const float* inb    = (const float*)d_in[6];
  const float* outw   = (const float*)d_in[7];
  const float* outb   = (const float*)d_in[8];
  const float* bw     = (const float*)d_in[9];
  const int*   coords = (const int*)d_in[10];
  const int N = in_sizes[0] / C;
  const int NPER = N / NB;
  const int NBLK = (N + 63) / 64;

  char* ws = (char*)d_ws;
  size_t off = 0;
  auto alloc = [&](size_t bytes) -> char* {
    char* r = ws + off; off += (bytes + 255) & ~(size_t)255; return r;
  };
  int* grid_h            = (int*)alloc((size_t)NB * GRID3 * 4);          // 33.5 MB (no memset)
  unsigned short* featsb = (unsigned short*)alloc((size_t)N * C * 2);    // 25.6 MB
  unsigned short* convwt = (unsigned short*)alloc((size_t)27 * C * C * 2);
  unsigned short* wq     = (unsigned short*)alloc((size_t)C * C * 2);
  unsigned short* wkvT   = (unsigned short*)alloc((size_t)2 * C * C * 2);
  unsigned short* w2b    = (unsigned short*)alloc((size_t)C * C * 2);
  float* b2              = (float*)alloc(512);
  float* xconv           = (float*)alloc((size_t)N * C * 4);             // 51.2 MB
  unsigned short* qb     = (unsigned short*)alloc((size_t)N * C * 2);    // 25.6 MB dedicated
  int2* pairs            = (int2*)alloc((size_t)27 * PCAP * 8);          // 1.7 MB
  float* spgs            = (float*)alloc((size_t)STAT_BLK * 256 * 4);    // 1 MB
  float* dpart           = (float*)alloc((size_t)DEN_BLK * 128 * 4);     // 0.5 MB
  float* zero_base       = (float*)alloc((size_t)512 * 4);
  float* gsum   = zero_base;
  float* gsq    = zero_base + 128;
  float* denom  = zero_base + 256;
  int*   gcnt   = (int*)(zero_base + 384);
  float* invden = (float*)alloc(512);
  float* scalev = (float*)alloc(512);
  float* shiftv = (float*)alloc(512);
  float* kh     = (float*)alloc((size_t)NB * KSLOT * C * 4);
  float* vh     = (float*)alloc((size_t)NB * KSLOT * C * 4);
  // aliases (lifetimes disjoint):
  float* pbuf = (float*)grid_h;                  // grid dead after pairk; 16.8 <= 33.5 MB OK
  unsigned short* o_bf = featsb;                 // featsb dead after scatk

  (void)hipMemsetAsync(zero_base, 0, (size_t)512 * 4, stream);
  prepk<<<2048, 256, 0, stream>>>(feats, convw, inw, featsb, convwt, wq, wkvT, (long)N * C);
  w2k<<<128, 128, 0, stream>>>(bw, outw, outb, w2b, b2);
  scatterk<<<(N + 255) / 256, 256, 0, stream>>>(coords, grid_h, N);
  pairk<<<(N + 255) / 256, 256, 0, stream>>>(coords, grid_h, pairs, gcnt, N);
  // grid_h dead; pbuf aliases it
  denomk<<<DEN_BLK, 256, 0, stream>>>(probs, coords, dpart, N);
  gemm128<<<NBLK, 256, 0, stream>>>(featsb, convwt + 13 * C * C, nullptr, 1.f, xconv, nullptr, N);
  scatk<<<dim3(26, 32), 256, 0, stream>>>(featsb, convwt, pairs, gcnt, xconv, N);
  statsk<<<STAT_BLK, 256, 0, stream>>>(xconv, spgs, N);
  {
    dim3 rg(3, 8);
    reduk<<<rg, 128, 0, stream>>>(spgs, dpart, gsum, gsq, denom);
  }
  finalizek<<<1, 128, 0, stream>>>(gsum, gsq, gamma, beta, denom, scalev, shiftv, invden, N);
  ctx2k<<<NB * CTX_BPB, 256, 0, stream>>>(xconv, probs, scalev, shiftv, pbuf, NPER);
  kvk<<<NB * KSLOT, 256, 0, stream>>>(pbuf, invden, wkvT, inb, kh, vh);
  gemm128f<<<NBLK, 256, 0, stream>>>(xconv, wq, inb, scalev, shiftv, 0.25f, qb, N);
  dim3 agrid((NPER + 63) / 64, NB);
  attn3k<<<agrid, 256, 0, stream>>>(qb, kh, vh, o_bf, NPER);
  gemm128<<<NBLK, 256, 0, stream>>>(o_bf, w2b, b2, 1.f, (float*)d_out, nullptr, N);
}